// Round 6
// baseline (192.990 us; speedup 1.0000x reference)
//
#include <hip/hip_runtime.h>
#include <math.h>

#define NB 512      // graph pairs
#define MM 64       // nodes per graph
#define EPGc 512    // edges per graph

typedef __attribute__((ext_vector_type(8))) short s16x8;
typedef __attribute__((ext_vector_type(4))) float f32x4;

__device__ __forceinline__ unsigned short f2bf(float f) {
  union { float f; unsigned int u; } c; c.f = f;
  unsigned int u = c.u;
  return (unsigned short)((u + 0x7FFFu + ((u >> 16) & 1u)) >> 16);   // RNE
}
__device__ __forceinline__ float bf2f(unsigned short h) {
  union { unsigned int u; float f; } c; c.u = ((unsigned int)h) << 16;
  return c.f;
}

// acc[j] += sum_kk a[kk] * b_kk[j]
__device__ __forceinline__ void fma4x4(float (&acc)[4], const float4 a,
    const float4 b0, const float4 b1, const float4 b2, const float4 b3)
{
  acc[0] = fmaf(a.x, b0.x, acc[0]); acc[0] = fmaf(a.y, b1.x, acc[0]);
  acc[0] = fmaf(a.z, b2.x, acc[0]); acc[0] = fmaf(a.w, b3.x, acc[0]);
  acc[1] = fmaf(a.x, b0.y, acc[1]); acc[1] = fmaf(a.y, b1.y, acc[1]);
  acc[1] = fmaf(a.z, b2.y, acc[1]); acc[1] = fmaf(a.w, b3.y, acc[1]);
  acc[2] = fmaf(a.x, b0.z, acc[2]); acc[2] = fmaf(a.y, b1.z, acc[2]);
  acc[2] = fmaf(a.z, b2.z, acc[2]); acc[2] = fmaf(a.w, b3.z, acc[2]);
  acc[3] = fmaf(a.x, b0.w, acc[3]); acc[3] = fmaf(a.y, b1.w, acc[3]);
  acc[3] = fmaf(a.z, b2.w, acc[3]); acc[3] = fmaf(a.w, b3.w, acc[3]);
}

// ----------------------------- GCN: dense-adjacency, register-tiled LDS GEMMs -----------------------------
template<int Fin, int Fout, bool RELU>
__device__ __forceinline__ void gcn_layer(
    const float* __restrict__ W, const float* __restrict__ bias,
    const float* sA, float* sh, float* st, float* sW,
    float* __restrict__ outG, int g, int tid)
{
  constexpr int SIN = Fin + 4;
  constexpr int SOUT = Fout + 4;
  constexpr int TPR = Fout / 4;
  constexpr int TR  = (Fout == 64) ? 4 : (Fout == 32 ? 2 : 1);
  const int n0 = (tid / TPR) * TR;
  const int f0 = (tid % TPR) * 4;

  for (int i = tid; i < Fin * Fout / 4; i += 256)
    *reinterpret_cast<float4*>(sW + i * 4) = *reinterpret_cast<const float4*>(W + i * 4);
  __syncthreads();

  {
    float acc[TR][4];
#pragma unroll
    for (int i = 0; i < TR; ++i) { acc[i][0] = 0; acc[i][1] = 0; acc[i][2] = 0; acc[i][3] = 0; }
#pragma unroll
    for (int k = 0; k < Fin; k += 4) {
      float4 b0 = *reinterpret_cast<const float4*>(sW + (k + 0) * Fout + f0);
      float4 b1 = *reinterpret_cast<const float4*>(sW + (k + 1) * Fout + f0);
      float4 b2 = *reinterpret_cast<const float4*>(sW + (k + 2) * Fout + f0);
      float4 b3 = *reinterpret_cast<const float4*>(sW + (k + 3) * Fout + f0);
#pragma unroll
      for (int i = 0; i < TR; ++i) {
        float4 a = *reinterpret_cast<const float4*>(sh + (n0 + i) * SIN + k);
        fma4x4(acc[i], a, b0, b1, b2, b3);
      }
    }
#pragma unroll
    for (int i = 0; i < TR; ++i)
      *reinterpret_cast<float4*>(st + (n0 + i) * Fout + f0) =
          make_float4(acc[i][0], acc[i][1], acc[i][2], acc[i][3]);
  }
  __syncthreads();

  {
    float acc[TR][4];
#pragma unroll
    for (int i = 0; i < TR; ++i) { acc[i][0] = 0; acc[i][1] = 0; acc[i][2] = 0; acc[i][3] = 0; }
#pragma unroll
    for (int k = 0; k < 64; k += 4) {
      float4 b0 = *reinterpret_cast<const float4*>(st + (k + 0) * Fout + f0);
      float4 b1 = *reinterpret_cast<const float4*>(st + (k + 1) * Fout + f0);
      float4 b2 = *reinterpret_cast<const float4*>(st + (k + 2) * Fout + f0);
      float4 b3 = *reinterpret_cast<const float4*>(st + (k + 3) * Fout + f0);
#pragma unroll
      for (int i = 0; i < TR; ++i) {
        float4 a = *reinterpret_cast<const float4*>(sA + (n0 + i) * 68 + k);
        fma4x4(acc[i], a, b0, b1, b2, b3);
      }
    }
    float4 bv = *reinterpret_cast<const float4*>(bias + f0);
#pragma unroll
    for (int i = 0; i < TR; ++i) {
      float4 v = make_float4(acc[i][0] + bv.x, acc[i][1] + bv.y,
                             acc[i][2] + bv.z, acc[i][3] + bv.w);
      *reinterpret_cast<float4*>(outG + ((size_t)(g * MM + n0 + i) * Fout) + f0) = v;
      float4 r = RELU ? make_float4(fmaxf(v.x, 0.f), fmaxf(v.y, 0.f),
                                    fmaxf(v.z, 0.f), fmaxf(v.w, 0.f)) : v;
      *reinterpret_cast<float4*>(sh + (n0 + i) * SOUT + f0) = r;
    }
  }
  __syncthreads();
}

__global__ __launch_bounds__(256) void gcn_kernel(
    const float* __restrict__ xq, const float* __restrict__ xc,
    const int* __restrict__ srcq, const int* __restrict__ dstq,
    const int* __restrict__ srcc, const int* __restrict__ dstc,
    const float* __restrict__ Wg0, const float* __restrict__ bg0,
    const float* __restrict__ Wg1, const float* __restrict__ bg1,
    const float* __restrict__ Wg2, const float* __restrict__ bg2,
    float* __restrict__ qf0, float* __restrict__ qf1, float* __restrict__ qf2,
    float* __restrict__ cf0, float* __restrict__ cf1, float* __restrict__ cf2)
{
  __shared__ __align__(16) float sA[64 * 68];
  __shared__ __align__(16) float sh[64 * 68];
  __shared__ __align__(16) float st[64 * 64];
  __shared__ __align__(16) float sW[2048];
  __shared__ float sDinv[MM];
  __shared__ int sDeg[MM];

  const int g = blockIdx.x;
  const int which = blockIdx.y;
  const float* x = which ? xc : xq;
  const int* src = which ? srcc : srcq;
  const int* dst = which ? dstc : dstq;
  float* f0p = which ? cf0 : qf0;
  float* f1p = which ? cf1 : qf1;
  float* f2p = which ? cf2 : qf2;
  const int tid = threadIdx.x;

  for (int i = tid; i < 64 * 68; i += 256) sA[i] = 0.f;
  if (tid < MM) sDeg[tid] = 1;
  __syncthreads();
  for (int e = tid; e < EPGc; e += 256)
    atomicAdd(&sDeg[dst[g * EPGc + e] - g * MM], 1);
  __syncthreads();
  if (tid < MM) sDinv[tid] = rsqrtf((float)sDeg[tid]);
  __syncthreads();
  for (int e = tid; e < EPGc; e += 256) {
    int s = src[g * EPGc + e] - g * MM;
    int d = dst[g * EPGc + e] - g * MM;
    atomicAdd(&sA[d * 68 + s], sDinv[s] * sDinv[d]);
  }
  if (tid < MM) atomicAdd(&sA[tid * 68 + tid], sDinv[tid] * sDinv[tid]);
  for (int i = tid; i < 512; i += 256) {
    float4 v = *reinterpret_cast<const float4*>(x + (size_t)g * 2048 + i * 4);
    int n = (i * 4) >> 5, k = (i * 4) & 31;
    *reinterpret_cast<float4*>(sh + n * 36 + k) = v;
  }
  __syncthreads();

  gcn_layer<32, 64, true >(Wg0, bg0, sA, sh, st, sW, f0p, g, tid);
  gcn_layer<64, 32, true >(Wg1, bg1, sA, sh, st, sW, f1p, g, tid);
  gcn_layer<32, 16, false>(Wg2, bg2, sA, sh, st, sW, f2p, g, tid);
}

// ----------------------------- conv2 weight prepack (unchanged, verified) -----------------------------
__global__ __launch_bounds__(256) void pack_w(const float* __restrict__ cw1,
                                              unsigned short* __restrict__ packA)
{
  int i = blockIdx.x * 256 + threadIdx.x;
  if (i >= 3 * 7 * 64 * 8) return;
  int j = i & 7, l = (i >> 3) & 63, g = (i >> 9) % 7, lvl = i / 3584;
  int oc = l & 15, sg = l >> 4;
  int s = g * 4 + sg;
  float v = 0.f;
  if (s < 25) v = cw1[((size_t)(lvl * 16 + oc) * 8 + j) * 25 + s];
  packA[i] = f2bf(v);
}

// ----------------------------- conv1 weight prepack: A-frag, oc=lane&15, k=u*8+v (u=gg*4+q, v=j) ---------
__global__ __launch_bounds__(256) void pack_w1(const float* __restrict__ cw0,
                                               unsigned short* __restrict__ packW1)
{
  int i = blockIdx.x * 256 + threadIdx.x;   // 3*2*64*8 = 3072
  if (i >= 3072) return;
  int j = i & 7, lane = (i >> 3) & 63, gg = (i >> 9) & 1, lvl = i >> 10;
  int oc = lane & 15, q = lane >> 4;
  int u = gg * 4 + q;
  float v = 0.f;
  if (oc < 8 && u < 5 && j < 5)
    v = cw0[((size_t)(lvl * 8 + oc)) * 25 + u * 5 + j];
  packW1[i] = f2bf(v);
}

// ----------------------------- Wl0 prepack: bf16, transposed to [n][k] -----------------------------
__global__ __launch_bounds__(256) void pack_wl0(const float* __restrict__ Wl0,
                                                unsigned short* __restrict__ WT)
{
  __shared__ float tile[64][65];
  const int kb = blockIdx.x * 64;
  const int nb = blockIdx.y * 64;
  const int tid = threadIdx.x;
#pragma unroll
  for (int i = 0; i < 16; ++i) {
    int idx = i * 256 + tid, kk = idx >> 6, nn = idx & 63;
    tile[kk][nn] = Wl0[(size_t)(kb + kk) * 256 + nb + nn];
  }
  __syncthreads();
#pragma unroll
  for (int i = 0; i < 16; ++i) {
    int idx = i * 256 + tid, nn = idx >> 6, kk = idx & 63;
    WT[(size_t)(nb + nn) * 12288 + kb + kk] = f2bf(tile[kk][nn]);
  }
}

// ----------------------------- fused sim(MFMA) + conv1(MFMA) + conv2(MFMA) + pools -----------------------------
// sim via MFMA: qbf/cbf bf16 [64][SQ], ssim bf16 [72 rows][80 cols] (halo 2; rows 68..71 zero for the
// zero-padded u=5..7 taps of conv1). Stride 80 => conv1's 4 q-row groups hit disjoint bank octets.
template<int F>
__device__ __forceinline__ void sim_mfma(const float* __restrict__ qf,
    const float* __restrict__ cf, unsigned short* qbf, unsigned short* cbf,
    unsigned short* ssim, int g, int tid)
{
  constexpr int SQ = (F == 16) ? 40 : F + 8;
  // zero ssim 72x80 = 5760 u16 = 2880 u32 (halo + pad rows)
  for (int i = tid; i < 2880; i += 256)
    reinterpret_cast<unsigned int*>(ssim)[i] = 0u;
  // stage qf, cf -> bf16, k-contiguous
  for (int i = tid; i < 64 * F / 8; i += 256) {
    int row = (i * 8) / F, k = (i * 8) % F;
    const float* qs = qf + (size_t)g * 64 * F + i * 8;
    const float* cs = cf + (size_t)g * 64 * F + i * 8;
    float4 q0 = *reinterpret_cast<const float4*>(qs);
    float4 q1 = *reinterpret_cast<const float4*>(qs + 4);
    float4 c0 = *reinterpret_cast<const float4*>(cs);
    float4 c1 = *reinterpret_cast<const float4*>(cs + 4);
    s16x8 qp, cp;
    qp[0] = (short)f2bf(q0.x); qp[1] = (short)f2bf(q0.y); qp[2] = (short)f2bf(q0.z); qp[3] = (short)f2bf(q0.w);
    qp[4] = (short)f2bf(q1.x); qp[5] = (short)f2bf(q1.y); qp[6] = (short)f2bf(q1.z); qp[7] = (short)f2bf(q1.w);
    cp[0] = (short)f2bf(c0.x); cp[1] = (short)f2bf(c0.y); cp[2] = (short)f2bf(c0.z); cp[3] = (short)f2bf(c0.w);
    cp[4] = (short)f2bf(c1.x); cp[5] = (short)f2bf(c1.y); cp[6] = (short)f2bf(c1.z); cp[7] = (short)f2bf(c1.w);
    *reinterpret_cast<s16x8*>(qbf + row * SQ + k) = qp;
    *reinterpret_cast<s16x8*>(cbf + row * SQ + k) = cp;
  }
  if (F == 16) {  // zero-pad k = 16..31 (fragments read k<32)
    for (int i = tid; i < 128; i += 256) {
      int row = i >> 1, h = (i & 1) * 8;
      s16x8 zz = {0, 0, 0, 0, 0, 0, 0, 0};
      *reinterpret_cast<s16x8*>(qbf + row * SQ + 16 + h) = zz;
      *reinterpret_cast<s16x8*>(cbf + row * SQ + 16 + h) = zz;
    }
  }
  __syncthreads();

  const int lane = tid & 63, wave = tid >> 6;
  const int c = lane & 15, q = lane >> 4;
  constexpr int NK = (F == 64) ? 2 : 1;

  f32x4 acc[4];
#pragma unroll
  for (int nt = 0; nt < 4; ++nt) acc[nt] = (f32x4){0.f, 0.f, 0.f, 0.f};
#pragma unroll
  for (int ks = 0; ks < NK; ++ks) {
    s16x8 af = *reinterpret_cast<const s16x8*>(qbf + (wave * 16 + c) * SQ + ks * 32 + q * 8);
#pragma unroll
    for (int nt = 0; nt < 4; ++nt) {
      s16x8 bf = *reinterpret_cast<const s16x8*>(cbf + (nt * 16 + c) * SQ + ks * 32 + q * 8);
      acc[nt] = __builtin_amdgcn_mfma_f32_16x16x32_bf16(af, bf, acc[nt], 0, 0, 0);
    }
  }
  // D: col = lane&15 (= cf row n), row = q*4 + r (= qf row m)
  const int wbase = (wave * 16 + q * 4 + 2) * 80 + (c + 2);
#pragma unroll
  for (int nt = 0; nt < 4; ++nt)
#pragma unroll
    for (int r = 0; r < 4; ++r)
      ssim[wbase + r * 80 + nt * 16] = f2bf(acc[nt][r]);
  __syncthreads();
}

// conv1 via MFMA (K=64: u=gg*4+q, v=j; taps u,v>=5 zero in A) + in-register 2x2 pool via shfl_xor
__device__ __forceinline__ void conv1_mfma(const unsigned short* ssim,
    unsigned short* p1u, const unsigned short* __restrict__ packW1,
    const float* __restrict__ cb0, int lvl, int tid)
{
  const int lane = tid & 63, wave = tid >> 6;
  const int c = lane & 15, q = lane >> 4;

  // zero p1ci halo frame (272 cells, strided: > blockDim!)
  for (int h = tid; h < 272; h += 256) {
    int r, cc;
    if (h < 72)       { r = h / 36;             cc = h % 36; }
    else if (h < 144) { r = 34 + (h - 72) / 36; cc = (h - 72) % 36; }
    else { int z = h - 144; r = 2 + (z >> 2); int wq = z & 3; cc = (wq < 2) ? wq : 32 + wq; }
    s16x8 zz = {0, 0, 0, 0, 0, 0, 0, 0};
    *reinterpret_cast<s16x8*>(p1u + (r * 36 + cc) * 8) = zz;
  }

  s16x8 aw0 = *reinterpret_cast<const s16x8*>(packW1 + ((size_t)(lvl * 2 + 0) * 64 + lane) * 8);
  s16x8 aw1 = *reinterpret_cast<const s16x8*>(packW1 + ((size_t)(lvl * 2 + 1) * 64 + lane) * 8);
  float bias[4];
#pragma unroll
  for (int r = 0; r < 4; ++r) bias[r] = cb0[lvl * 8 + ((q * 4 + r) & 7)];

  for (int pp = 0; pp < 8; ++pp) {
    const int Y = wave * 8 + pp;                    // pooled row
    const int vaddr = (2 * Y + q) * 80 + c;         // per-lane base; all else imm offsets
#pragma unroll
    for (int Xi = 0; Xi < 4; ++Xi) {
      f32x4 at = {0.f, 0.f, 0.f, 0.f}, ab = {0.f, 0.f, 0.f, 0.f};
#pragma unroll
      for (int gg = 0; gg < 2; ++gg) {
        s16x8 bt, bb_;
#pragma unroll
        for (int j = 0; j < 8; ++j) bt[j]  = (short)ssim[vaddr + gg * 320 + Xi * 16 + j];
#pragma unroll
        for (int j = 0; j < 8; ++j) bb_[j] = (short)ssim[vaddr + 80 + gg * 320 + Xi * 16 + j];
        const s16x8 aw = gg ? aw1 : aw0;
        at = __builtin_amdgcn_mfma_f32_16x16x32_bf16(aw, bt,  at, 0, 0, 0);
        ab = __builtin_amdgcn_mfma_f32_16x16x32_bf16(aw, bb_, ab, 0, 0, 0);
      }
      unsigned short pk[4];
#pragma unroll
      for (int r = 0; r < 4; ++r) {
        float m = fmaxf(at[r], ab[r]);              // vertical pool
        m = fmaxf(m, __shfl_xor(m, 1));             // horizontal pool (pixel pair)
        pk[r] = f2bf(fmaxf(m + bias[r], 0.f));
      }
      if ((lane & 1) == 0 && q < 2) {               // oc 0..7 live in q=0,1
        int Xp = (Xi * 16 + c) >> 1;
        unsigned int w0 = (unsigned int)pk[0] | ((unsigned int)pk[1] << 16);
        unsigned int w1 = (unsigned int)pk[2] | ((unsigned int)pk[3] << 16);
        *reinterpret_cast<uint2*>(p1u + (((Y + 2) * 36) + (Xp + 2)) * 8 + q * 4) =
            make_uint2(w0, w1);
      }
    }
  }
  __syncthreads();
}

__global__ __launch_bounds__(256) void simconv_kernel(
    const float* __restrict__ qf0, const float* __restrict__ qf1, const float* __restrict__ qf2,
    const float* __restrict__ cf0, const float* __restrict__ cf1, const float* __restrict__ cf2,
    const float* __restrict__ cb0, const float* __restrict__ cb1,
    const unsigned short* __restrict__ packA, const unsigned short* __restrict__ packW1,
    float* __restrict__ hcat)
{
  __shared__ __align__(16) unsigned short smem[26752];   // 53504 B -> 3 blocks/CU
  // lifetimes: p1u [0,10368) conv1->conv2 ; qbf/cbf [10368,19584) sim only ;
  //            ssim [19584,25344) sim->conv1 ; c2u [10368,26752) conv2->pool2
  unsigned short* p1u  = smem;
  unsigned short* qbf  = smem + 10368;
  unsigned short* cbf  = smem + 14976;
  unsigned short* ssim = smem + 19584;
  unsigned short* c2u  = smem + 10368;

  const int g = blockIdx.x, lvl = blockIdx.y, tid = threadIdx.x;

  if (lvl == 0)      sim_mfma<64>(qf0, cf0, qbf, cbf, ssim, g, tid);
  else if (lvl == 1) sim_mfma<32>(qf1, cf1, qbf, cbf, ssim, g, tid);
  else               sim_mfma<16>(qf2, cf2, qbf, cbf, ssim, g, tid);

  conv1_mfma(ssim, p1u, packW1, cb0, lvl, tid);

  // ---- conv2 via MFMA (unchanged, verified): out[16 oc][1024 pix] ----
  {
    const int lane = tid & 63, wave = tid >> 6;
    const int col = lane & 15, q = lane >> 4;

    s16x8 afr[7];
#pragma unroll
    for (int gg = 0; gg < 7; ++gg)
      afr[gg] = *reinterpret_cast<const s16x8*>(packA + ((size_t)(lvl * 7 + gg) * 64 + lane) * 8);

    int off[7];
#pragma unroll
    for (int gg = 0; gg < 7; ++gg) {
      int s = gg * 4 + q; if (s > 24) s = 24;
      off[gg] = (s / 5) * 288 + (s % 5) * 8;
    }

    for (int tt = 0; tt < 16; ++tt) {
      int t = wave * 16 + tt;
      int base = (t >> 1) * 288 + (t & 1) * 128 + col * 8;
      f32x4 acc = {0.f, 0.f, 0.f, 0.f};
#pragma unroll
      for (int gg = 0; gg < 7; ++gg) {
        s16x8 b = *reinterpret_cast<const s16x8*>(p1u + base + off[gg]);
        acc = __builtin_amdgcn_mfma_f32_16x16x32_bf16(afr[gg], b, acc, 0, 0, 0);
      }
      int pix = t * 16 + col;
      unsigned short pk[4];
#pragma unroll
      for (int r = 0; r < 4; ++r) pk[r] = f2bf(acc[r]);
      unsigned int w0 = (unsigned int)pk[0] | ((unsigned int)pk[1] << 16);
      unsigned int w1 = (unsigned int)pk[2] | ((unsigned int)pk[3] << 16);
      *reinterpret_cast<uint2*>(c2u + pix * 16 + q * 4) = make_uint2(w0, w1);
    }
  }
  __syncthreads();

  // ---- pool2 2x2 + bias + relu -> hcat ----
  {
    const float* bb = cb1 + lvl * 16;
#pragma unroll
    for (int m = 0; m < 4; ++m) {
      int u = m * 256 + tid;
      int q = u & 3, p = u >> 2;
      int py = p >> 4, px = p & 15;
      float best[4] = {-1e30f, -1e30f, -1e30f, -1e30f};
#pragma unroll
      for (int dy = 0; dy < 2; ++dy)
#pragma unroll
        for (int dx = 0; dx < 2; ++dx) {
          uint2 dv = *reinterpret_cast<const uint2*>(
              c2u + (((2 * py + dy) * 32 + 2 * px + dx) * 16 + q * 4));
          best[0] = fmaxf(best[0], bf2f((unsigned short)(dv.x & 0xFFFF)));
          best[1] = fmaxf(best[1], bf2f((unsigned short)(dv.x >> 16)));
          best[2] = fmaxf(best[2], bf2f((unsigned short)(dv.y & 0xFFFF)));
          best[3] = fmaxf(best[3], bf2f((unsigned short)(dv.y >> 16)));
        }
#pragma unroll
      for (int r = 0; r < 4; ++r) {
        int oc = q * 4 + r;
        float val = fmaxf(best[r] + bb[oc], 0.f);
        hcat[((size_t)g * 48 + lvl * 16 + oc) * 256 + p] = val;
      }
    }
  }
}

// ----------------------------- linear 0 via MFMA (unchanged, verified) -----------------------------
__global__ __launch_bounds__(256) void init_l0(const float* __restrict__ bl0, float* __restrict__ l0)
{
  int i = blockIdx.x * 256 + threadIdx.x;
  l0[i] = bl0[i & 255];
}

__global__ __launch_bounds__(256) void lin0_kernel(
    const float* __restrict__ A, const unsigned short* __restrict__ WT,
    float* __restrict__ l0)
{
  __shared__ __align__(16) unsigned short sAb[64 * 72];
  __shared__ __align__(16) unsigned short sBb[64 * 72];
  const int rb = blockIdx.x * 64;
  const int cb = blockIdx.y * 64;
  const int k0 = blockIdx.z * 768;
  const int tid = threadIdx.x;
  const int lane = tid & 63, wave = tid >> 6;
  const int wm = wave >> 1, wn = wave & 1;
  const int c = lane & 15, kg = lane >> 4;
  const int srow = tid >> 2;
  const int skq  = (tid & 3) * 16;

  f32x4 acc[2][2];
#pragma unroll
  for (int i = 0; i < 2; ++i)
#pragma unroll
    for (int j = 0; j < 2; ++j) acc[i][j] = (f32x4){0.f, 0.f, 0.f, 0.f};

  for (int kt = 0; kt < 768; kt += 64) {
    {
      const float* src = A + (size_t)(rb + srow) * 12288 + k0 + kt + skq;
      float4 v0 = *reinterpret_cast<const float4*>(src + 0);
      float4 v1 = *reinterpret_cast<const float4*>(src + 4);
      float4 v2 = *reinterpret_cast<const float4*>(src + 8);
      float4 v3 = *reinterpret_cast<const float4*>(src + 12);
      s16x8 p0, p1;
      p0[0] = (short)f2bf(v0.x); p0[1] = (short)f2bf(v0.y); p0[2] = (short)f2bf(v0.z); p0[3] = (short)f2bf(v0.w);
      p0[4] = (short)f2bf(v1.x); p0[5] = (short)f2bf(v1.y); p0[6] = (short)f2bf(v1.z); p0[7] = (short)f2bf(v1.w);
      p1[0] = (short)f2bf(v2.x); p1[1] = (short)f2bf(v2.y); p1[2] = (short)f2bf(v2.z); p1[3] = (short)f2bf(v2.w);
      p1[4] = (short)f2bf(v3.x); p1[5] = (short)f2bf(v3.y); p1[6] = (short)f2bf(v3.z); p1[7] = (short)f2bf(v3.w);
      *reinterpret_cast<s16x8*>(sAb + srow * 72 + skq)     = p0;
      *reinterpret_cast<s16x8*>(sAb + srow * 72 + skq + 8) = p1;
    }
    {
      const unsigned short* src = WT + (size_t)(cb + srow) * 12288 + k0 + kt + skq;
      s16x8 w0 = *reinterpret_cast<const s16x8*>(src);
      s16x8 w1 = *reinterpret_cast<const s16x8*>(src + 8);
      *reinterpret_cast<s16x8*>(sBb + srow * 72 + skq)     = w0;
      *reinterpret_cast<s16x8*>(sBb + srow * 72 + skq + 8) = w1;
    }
    __syncthreads();

#pragma unroll
    for (int kb = 0; kb < 64; kb += 32) {
      s16x8 a0 = *reinterpret_cast<const s16x8*>(sAb + (wm * 32 +  0 + c) * 72 + kb + kg * 8);
      s16x8 a1 = *reinterpret_cast<const s16x8*>(sAb + (wm * 32 + 16 + c) * 72 + kb + kg * 8);
      s16x8 b0 = *reinterpret_cast<const s16x8*>(sBb + (wn * 32 +  0 + c) * 72 + kb + kg * 8);
      s16x8 b1 = *reinterpret_cast<const s16x8*>(sBb + (wn * 32 + 16 + c) * 72 + kb + kg * 8);
      acc[0][0] = __builtin_amdgcn_mfma_f32_16x16x32_bf16(a0, b0, acc[0][0], 0, 0, 0);
      acc[0][1] = __builtin_amdgcn_mfma_f32_16x16x32_bf16(a0, b1, acc[0][1], 0, 0, 0);
      acc[1][0] = __builtin_amdgcn_mfma_f32_16x16x32_bf16(a1, b0, acc[1][0], 0, 0, 0);
      acc[1][1] = __builtin_amdgcn_mfma_f32_16x16x32_bf16(a1, b1, acc[1][1], 0, 0, 0);
    }
    __syncthreads();
  }

#pragma unroll
  for (int i = 0; i < 2; ++i)
#pragma unroll
    for (int j = 0; j < 2; ++j)
#pragma unroll
      for (int r = 0; r < 4; ++r) {
        int row = rb + wm * 32 + i * 16 + kg * 4 + r;
        int col = cb + wn * 32 + j * 16 + c;
        atomicAdd(&l0[(size_t)row * 256 + col], acc[i][j][r]);
      }
}

// ----------------------------- head -----------------------------
__global__ __launch_bounds__(64) void head_kernel(
    const float* __restrict__ l0, const float* __restrict__ Wl1, const float* __restrict__ bl1,
    const float* __restrict__ Wsc, const float* __restrict__ bsc, float* __restrict__ out)
{
  __shared__ float sr[256];
  const int b = blockIdx.x, j = threadIdx.x;
  for (int k = j; k < 256; k += 64) sr[k] = fmaxf(l0[(size_t)b * 256 + k], 0.f);
  __syncthreads();
  float acc = bl1[j];
  for (int k = 0; k < 256; ++k) acc = fmaf(sr[k], Wl1[k * 64 + j], acc);
  float v = fmaxf(acc, 0.f) * Wsc[j];
#pragma unroll
  for (int off = 32; off > 0; off >>= 1) v += __shfl_down(v, off);
  if (j == 0) out[b] = 1.f / (1.f + expf(-(v + bsc[0])));
}

// ----------------------------- launch -----------------------------
extern "C" void kernel_launch(void* const* d_in, const int* in_sizes, int n_in,
                              void* d_out, int out_size, void* d_ws, size_t ws_size,
                              hipStream_t stream)
{
  (void)in_sizes; (void)n_in; (void)out_size; (void)ws_size;
  const float* x_q = (const float*)d_in[0];
  const float* x_c = (const float*)d_in[1];
  const int*   src_q = (const int*)d_in[2];
  const int*   dst_q = (const int*)d_in[3];
  const int*   src_c = (const int*)d_in[4];
  const int*   dst_c = (const int*)d_in[5];
  const float* Wg0 = (const float*)d_in[6];
  const float* bg0 = (const float*)d_in[7];
  const float* Wg1 = (const float*)d_in[8];
  const float* bg1 = (const float*)d_in[9];
  const float* Wg2 = (const float*)d_in[10];
  const float* bg2 = (const float*)d_in[11];
  const float* cw0 = (const float*)d_in[12];
  const float* cb0 = (const float*)d_in[13];
  const float* cw1 = (const float*)d_in[14];
  const float* cb1 = (const float*)d_in[15];
  const float* Wl0 = (const float*)d_in[16];
  const float* bl0 = (const float*)d_in[17];
  const float* Wl1 = (const float*)d_in[18];
  const float* bl1 = (const float*)d_in[19];
  const float* Wsc = (const float*)d_in[20];
  const float* bsc = (const float*)d_in[21];
  float* out = (float*)d_out;

  float* ws = (float*)d_ws;
  float* qf0 = ws; ws += (size_t)NB * MM * 64;
  float* qf1 = ws; ws += (size_t)NB * MM * 32;
  float* qf2 = ws; ws += (size_t)NB * MM * 16;
  float* cf0 = ws; ws += (size_t)NB * MM * 64;
  float* cf1 = ws; ws += (size_t)NB * MM * 32;
  float* cf2 = ws; ws += (size_t)NB * MM * 16;
  float* hcat = ws; ws += (size_t)NB * 48 * 256;
  float* l0  = ws; ws += (size_t)NB * 256;
  unsigned short* packA  = (unsigned short*)ws; ws += 5376;   // 3*7*64*8 bf16
  unsigned short* packW1 = (unsigned short*)ws; ws += 1536;   // 3*2*64*8 bf16
  unsigned short* WT = (unsigned short*)ws; ws += (size_t)256 * 12288 / 2;

  pack_w<<<42, 256, 0, stream>>>(cw1, packA);
  pack_w1<<<12, 256, 0, stream>>>(cw0, packW1);
  pack_wl0<<<dim3(192, 4), 256, 0, stream>>>(Wl0, WT);

  gcn_kernel<<<dim3(NB, 2), 256, 0, stream>>>(x_q, x_c, src_q, dst_q, src_c, dst_c,
      Wg0, bg0, Wg1, bg1, Wg2, bg2, qf0, qf1, qf2, cf0, cf1, cf2);

  simconv_kernel<<<dim3(NB, 3), 256, 0, stream>>>(qf0, qf1, qf2, cf0, cf1, cf2,
      cb0, cb1, packA, packW1, hcat);

  init_l0<<<NB, 256, 0, stream>>>(bl0, l0);
  lin0_kernel<<<dim3(8, 4, 16), 256, 0, stream>>>(hcat, WT, l0);
  head_kernel<<<NB, 64, 0, stream>>>(l0, Wl1, bl1, Wsc, bsc, out);
}

// Round 7
// 138.811 us; speedup vs baseline: 1.3903x; 1.3903x over previous
//
#include <hip/hip_runtime.h>
#include <math.h>

#define NB 512      // graph pairs
#define MM 64       // nodes per graph
#define EPGc 512    // edges per graph

typedef __attribute__((ext_vector_type(8))) short s16x8;
typedef __attribute__((ext_vector_type(4))) float f32x4;

__device__ __forceinline__ unsigned short f2bf(float f) {
  union { float f; unsigned int u; } c; c.f = f;
  unsigned int u = c.u;
  return (unsigned short)((u + 0x7FFFu + ((u >> 16) & 1u)) >> 16);   // RNE
}
__device__ __forceinline__ float bf2f(unsigned short h) {
  union { unsigned int u; float f; } c; c.u = ((unsigned int)h) << 16;
  return c.f;
}

// acc[j] += sum_kk a[kk] * b_kk[j]
__device__ __forceinline__ void fma4x4(float (&acc)[4], const float4 a,
    const float4 b0, const float4 b1, const float4 b2, const float4 b3)
{
  acc[0] = fmaf(a.x, b0.x, acc[0]); acc[0] = fmaf(a.y, b1.x, acc[0]);
  acc[0] = fmaf(a.z, b2.x, acc[0]); acc[0] = fmaf(a.w, b3.x, acc[0]);
  acc[1] = fmaf(a.x, b0.y, acc[1]); acc[1] = fmaf(a.y, b1.y, acc[1]);
  acc[1] = fmaf(a.z, b2.y, acc[1]); acc[1] = fmaf(a.w, b3.y, acc[1]);
  acc[2] = fmaf(a.x, b0.z, acc[2]); acc[2] = fmaf(a.y, b1.z, acc[2]);
  acc[2] = fmaf(a.z, b2.z, acc[2]); acc[2] = fmaf(a.w, b3.z, acc[2]);
  acc[3] = fmaf(a.x, b0.w, acc[3]); acc[3] = fmaf(a.y, b1.w, acc[3]);
  acc[3] = fmaf(a.z, b2.w, acc[3]); acc[3] = fmaf(a.w, b3.w, acc[3]);
}

// ----------------------------- GCN: dense-adjacency, register-tiled LDS GEMMs (unchanged) ---------------
template<int Fin, int Fout, bool RELU>
__device__ __forceinline__ void gcn_layer(
    const float* __restrict__ W, const float* __restrict__ bias,
    const float* sA, float* sh, float* st, float* sW,
    float* __restrict__ outG, int g, int tid)
{
  constexpr int SIN = Fin + 4;
  constexpr int SOUT = Fout + 4;
  constexpr int TPR = Fout / 4;
  constexpr int TR  = (Fout == 64) ? 4 : (Fout == 32 ? 2 : 1);
  const int n0 = (tid / TPR) * TR;
  const int f0 = (tid % TPR) * 4;

  for (int i = tid; i < Fin * Fout / 4; i += 256)
    *reinterpret_cast<float4*>(sW + i * 4) = *reinterpret_cast<const float4*>(W + i * 4);
  __syncthreads();

  {
    float acc[TR][4];
#pragma unroll
    for (int i = 0; i < TR; ++i) { acc[i][0] = 0; acc[i][1] = 0; acc[i][2] = 0; acc[i][3] = 0; }
#pragma unroll
    for (int k = 0; k < Fin; k += 4) {
      float4 b0 = *reinterpret_cast<const float4*>(sW + (k + 0) * Fout + f0);
      float4 b1 = *reinterpret_cast<const float4*>(sW + (k + 1) * Fout + f0);
      float4 b2 = *reinterpret_cast<const float4*>(sW + (k + 2) * Fout + f0);
      float4 b3 = *reinterpret_cast<const float4*>(sW + (k + 3) * Fout + f0);
#pragma unroll
      for (int i = 0; i < TR; ++i) {
        float4 a = *reinterpret_cast<const float4*>(sh + (n0 + i) * SIN + k);
        fma4x4(acc[i], a, b0, b1, b2, b3);
      }
    }
#pragma unroll
    for (int i = 0; i < TR; ++i)
      *reinterpret_cast<float4*>(st + (n0 + i) * Fout + f0) =
          make_float4(acc[i][0], acc[i][1], acc[i][2], acc[i][3]);
  }
  __syncthreads();

  {
    float acc[TR][4];
#pragma unroll
    for (int i = 0; i < TR; ++i) { acc[i][0] = 0; acc[i][1] = 0; acc[i][2] = 0; acc[i][3] = 0; }
#pragma unroll
    for (int k = 0; k < 64; k += 4) {
      float4 b0 = *reinterpret_cast<const float4*>(st + (k + 0) * Fout + f0);
      float4 b1 = *reinterpret_cast<const float4*>(st + (k + 1) * Fout + f0);
      float4 b2 = *reinterpret_cast<const float4*>(st + (k + 2) * Fout + f0);
      float4 b3 = *reinterpret_cast<const float4*>(st + (k + 3) * Fout + f0);
#pragma unroll
      for (int i = 0; i < TR; ++i) {
        float4 a = *reinterpret_cast<const float4*>(sA + (n0 + i) * 68 + k);
        fma4x4(acc[i], a, b0, b1, b2, b3);
      }
    }
    float4 bv = *reinterpret_cast<const float4*>(bias + f0);
#pragma unroll
    for (int i = 0; i < TR; ++i) {
      float4 v = make_float4(acc[i][0] + bv.x, acc[i][1] + bv.y,
                             acc[i][2] + bv.z, acc[i][3] + bv.w);
      *reinterpret_cast<float4*>(outG + ((size_t)(g * MM + n0 + i) * Fout) + f0) = v;
      float4 r = RELU ? make_float4(fmaxf(v.x, 0.f), fmaxf(v.y, 0.f),
                                    fmaxf(v.z, 0.f), fmaxf(v.w, 0.f)) : v;
      *reinterpret_cast<float4*>(sh + (n0 + i) * SOUT + f0) = r;
    }
  }
  __syncthreads();
}

__global__ __launch_bounds__(256) void gcn_kernel(
    const float* __restrict__ xq, const float* __restrict__ xc,
    const int* __restrict__ srcq, const int* __restrict__ dstq,
    const int* __restrict__ srcc, const int* __restrict__ dstc,
    const float* __restrict__ Wg0, const float* __restrict__ bg0,
    const float* __restrict__ Wg1, const float* __restrict__ bg1,
    const float* __restrict__ Wg2, const float* __restrict__ bg2,
    float* __restrict__ qf0, float* __restrict__ qf1, float* __restrict__ qf2,
    float* __restrict__ cf0, float* __restrict__ cf1, float* __restrict__ cf2)
{
  __shared__ __align__(16) float sA[64 * 68];
  __shared__ __align__(16) float sh[64 * 68];
  __shared__ __align__(16) float st[64 * 64];
  __shared__ __align__(16) float sW[2048];
  __shared__ float sDinv[MM];
  __shared__ int sDeg[MM];

  const int g = blockIdx.x;
  const int which = blockIdx.y;
  const float* x = which ? xc : xq;
  const int* src = which ? srcc : srcq;
  const int* dst = which ? dstc : dstq;
  float* f0p = which ? cf0 : qf0;
  float* f1p = which ? cf1 : qf1;
  float* f2p = which ? cf2 : qf2;
  const int tid = threadIdx.x;

  for (int i = tid; i < 64 * 68; i += 256) sA[i] = 0.f;
  if (tid < MM) sDeg[tid] = 1;
  __syncthreads();
  for (int e = tid; e < EPGc; e += 256)
    atomicAdd(&sDeg[dst[g * EPGc + e] - g * MM], 1);
  __syncthreads();
  if (tid < MM) sDinv[tid] = rsqrtf((float)sDeg[tid]);
  __syncthreads();
  for (int e = tid; e < EPGc; e += 256) {
    int s = src[g * EPGc + e] - g * MM;
    int d = dst[g * EPGc + e] - g * MM;
    atomicAdd(&sA[d * 68 + s], sDinv[s] * sDinv[d]);
  }
  if (tid < MM) atomicAdd(&sA[tid * 68 + tid], sDinv[tid] * sDinv[tid]);
  for (int i = tid; i < 512; i += 256) {
    float4 v = *reinterpret_cast<const float4*>(x + (size_t)g * 2048 + i * 4);
    int n = (i * 4) >> 5, k = (i * 4) & 31;
    *reinterpret_cast<float4*>(sh + n * 36 + k) = v;
  }
  __syncthreads();

  gcn_layer<32, 64, true >(Wg0, bg0, sA, sh, st, sW, f0p, g, tid);
  gcn_layer<64, 32, true >(Wg1, bg1, sA, sh, st, sW, f1p, g, tid);
  gcn_layer<32, 16, false>(Wg2, bg2, sA, sh, st, sW, f2p, g, tid);
}

// ----------------------------- conv2 weight prepack (unchanged, verified) -----------------------------
__global__ __launch_bounds__(256) void pack_w(const float* __restrict__ cw1,
                                              unsigned short* __restrict__ packA)
{
  int i = blockIdx.x * 256 + threadIdx.x;
  if (i >= 3 * 7 * 64 * 8) return;
  int j = i & 7, l = (i >> 3) & 63, g = (i >> 9) % 7, lvl = i / 3584;
  int oc = l & 15, sg = l >> 4;
  int s = g * 4 + sg;
  float v = 0.f;
  if (s < 25) v = cw1[((size_t)(lvl * 16 + oc) * 8 + j) * 25 + s];
  packA[i] = f2bf(v);
}

// ----------------------------- conv1 weight prepack: 2-conv-rows-per-MFMA A layout ---------------------
// A rows m=0..7: oc=m, taps for conv row y0, u = gg*4+q.
// A rows m=8..15: oc=m-8, taps for conv row y0+1, tap u' = u-1.
__global__ __launch_bounds__(256) void pack_w1(const float* __restrict__ cw0,
                                               unsigned short* __restrict__ packW1)
{
  int i = blockIdx.x * 256 + threadIdx.x;   // 3*2*64*8 = 3072
  if (i >= 3072) return;
  int j = i & 7, lane = (i >> 3) & 63, gg = (i >> 9) & 1, lvl = i >> 10;
  int m = lane & 15, q = lane >> 4;
  int u = gg * 4 + q;
  int oc = m & 7;
  int up = (m < 8) ? u : (u - 1);
  float v = 0.f;
  if (up >= 0 && up < 5 && j < 5)
    v = cw0[((size_t)(lvl * 8 + oc)) * 25 + up * 5 + j];
  packW1[i] = f2bf(v);
}

// ----------------------------- Wl0 prepack (unchanged) -----------------------------
__global__ __launch_bounds__(256) void pack_wl0(const float* __restrict__ Wl0,
                                                unsigned short* __restrict__ WT)
{
  __shared__ float tile[64][65];
  const int kb = blockIdx.x * 64;
  const int nb = blockIdx.y * 64;
  const int tid = threadIdx.x;
#pragma unroll
  for (int i = 0; i < 16; ++i) {
    int idx = i * 256 + tid, kk = idx >> 6, nn = idx & 63;
    tile[kk][nn] = Wl0[(size_t)(kb + kk) * 256 + nb + nn];
  }
  __syncthreads();
#pragma unroll
  for (int i = 0; i < 16; ++i) {
    int idx = i * 256 + tid, nn = idx >> 6, kk = idx & 63;
    WT[(size_t)(nb + nn) * 12288 + kb + kk] = f2bf(tile[kk][nn]);
  }
}

// ----------------------------- fused sim(MFMA) + conv1(MFMA,2row) + conv2(MFMA,inreg-pool) -------------
// ssim stored as TWO bf16 copies [72 rows][72 cols]: cp0[y][x]=S(y,x), cp1[y][x]=S(y,x+1).
// Any 8-u16 window [s..s+7] = 4 aligned ds_read_b32 from copy[s&1] at s-(s&1).
template<int F>
__device__ __forceinline__ void sim_mfma(const float* __restrict__ qf,
    const float* __restrict__ cf, unsigned short* qbf, unsigned short* cbf,
    unsigned short* cp0, unsigned short* cp1, int g, int tid)
{
  constexpr int SQ = (F == 16) ? 40 : F + 8;
  // zero both copies (2*5184 u16 = 5184 u32, contiguous)
  {
    unsigned int* z = reinterpret_cast<unsigned int*>(cp0);
    for (int i = tid; i < 5184; i += 256) z[i] = 0u;
  }
  // stage qf, cf -> bf16, k-contiguous
  for (int i = tid; i < 64 * F / 8; i += 256) {
    int row = (i * 8) / F, k = (i * 8) % F;
    const float* qs = qf + (size_t)g * 64 * F + i * 8;
    const float* cs = cf + (size_t)g * 64 * F + i * 8;
    float4 q0 = *reinterpret_cast<const float4*>(qs);
    float4 q1 = *reinterpret_cast<const float4*>(qs + 4);
    float4 c0 = *reinterpret_cast<const float4*>(cs);
    float4 c1 = *reinterpret_cast<const float4*>(cs + 4);
    s16x8 qp, cp;
    qp[0] = (short)f2bf(q0.x); qp[1] = (short)f2bf(q0.y); qp[2] = (short)f2bf(q0.z); qp[3] = (short)f2bf(q0.w);
    qp[4] = (short)f2bf(q1.x); qp[5] = (short)f2bf(q1.y); qp[6] = (short)f2bf(q1.z); qp[7] = (short)f2bf(q1.w);
    cp[0] = (short)f2bf(c0.x); cp[1] = (short)f2bf(c0.y); cp[2] = (short)f2bf(c0.z); cp[3] = (short)f2bf(c0.w);
    cp[4] = (short)f2bf(c1.x); cp[5] = (short)f2bf(c1.y); cp[6] = (short)f2bf(c1.z); cp[7] = (short)f2bf(c1.w);
    *reinterpret_cast<s16x8*>(qbf + row * SQ + k) = qp;
    *reinterpret_cast<s16x8*>(cbf + row * SQ + k) = cp;
  }
  if (F == 16) {
    for (int i = tid; i < 128; i += 256) {
      int row = i >> 1, h = (i & 1) * 8;
      s16x8 zz = {0, 0, 0, 0, 0, 0, 0, 0};
      *reinterpret_cast<s16x8*>(qbf + row * SQ + 16 + h) = zz;
      *reinterpret_cast<s16x8*>(cbf + row * SQ + 16 + h) = zz;
    }
  }
  __syncthreads();

  const int lane = tid & 63, wave = tid >> 6;
  const int c = lane & 15, q = lane >> 4;
  constexpr int NK = (F == 64) ? 2 : 1;

  f32x4 acc[4];
#pragma unroll
  for (int nt = 0; nt < 4; ++nt) acc[nt] = (f32x4){0.f, 0.f, 0.f, 0.f};
#pragma unroll
  for (int ks = 0; ks < NK; ++ks) {
    s16x8 af = *reinterpret_cast<const s16x8*>(qbf + (wave * 16 + c) * SQ + ks * 32 + q * 8);
#pragma unroll
    for (int nt = 0; nt < 4; ++nt) {
      s16x8 bf = *reinterpret_cast<const s16x8*>(cbf + (nt * 16 + c) * SQ + ks * 32 + q * 8);
      acc[nt] = __builtin_amdgcn_mfma_f32_16x16x32_bf16(af, bf, acc[nt], 0, 0, 0);
    }
  }
  // D: image row i = wave*16 + q*4 + r, image col n = nt*16 + c.
  // stored: cp0[i+2][n+2], cp1[i+2][n+1]
#pragma unroll
  for (int nt = 0; nt < 4; ++nt)
#pragma unroll
    for (int r = 0; r < 4; ++r) {
      unsigned short bv = f2bf(acc[nt][r]);
      int row = wave * 16 + q * 4 + r + 2;
      int n = nt * 16 + c;
      cp0[row * 72 + n + 2] = bv;
      cp1[row * 72 + n + 1] = bv;
    }
  __syncthreads();
}

// conv1 via MFMA: one B-fragment feeds 2 conv rows (A rows 0..7 -> y0, 8..15 -> y0+1).
// Pool: vertical via shfl_xor(32) (q<->q+2), horizontal via shfl_xor(1).
__device__ __forceinline__ void conv1_mfma(const unsigned short* cp0, const unsigned short* cp1,
    unsigned short* p1u, const unsigned short* __restrict__ packW1,
    const float* __restrict__ cb0, int lvl, int tid)
{
  const int lane = tid & 63, wave = tid >> 6;
  const int c = lane & 15, q = lane >> 4;

  // zero p1ci halo frame (272 cells, strided)
  for (int h = tid; h < 272; h += 256) {
    int r, cc;
    if (h < 72)       { r = h / 36;             cc = h % 36; }
    else if (h < 144) { r = 34 + (h - 72) / 36; cc = (h - 72) % 36; }
    else { int z = h - 144; r = 2 + (z >> 2); int wq = z & 3; cc = (wq < 2) ? wq : 32 + wq; }
    s16x8 zz = {0, 0, 0, 0, 0, 0, 0, 0};
    *reinterpret_cast<s16x8*>(p1u + (r * 36 + cc) * 8) = zz;
  }

  s16x8 aw0 = *reinterpret_cast<const s16x8*>(packW1 + ((size_t)(lvl * 2 + 0) * 64 + lane) * 8);
  s16x8 aw1 = *reinterpret_cast<const s16x8*>(packW1 + ((size_t)(lvl * 2 + 1) * 64 + lane) * 8);
  float bias[4];
#pragma unroll
  for (int r = 0; r < 4; ++r) bias[r] = cb0[lvl * 8 + (q & 1) * 4 + r];

  const unsigned int* b32 = reinterpret_cast<const unsigned int*>((c & 1) ? cp1 : cp0);
  const int a2 = (c & ~1) >> 1;   // dword offset within row for this lane

  for (int pp = 0; pp < 8; ++pp) {
    const int Y = wave * 8 + pp;          // pooled row
    const int y0 = 2 * Y;
    const int r0 = (y0 + q) * 36;         // gg0: taps u=q        (dword row base, stride 72 u16)
    const int r1 = (y0 + 4 + q) * 36;     // gg1: taps u=4+q
#pragma unroll
    for (int Xi = 0; Xi < 4; ++Xi) {
      const int d0 = r0 + Xi * 8 + a2;
      const int d1 = r1 + Xi * 8 + a2;
      union { unsigned int d[4]; s16x8 v; } f0, f1;
      f0.d[0] = b32[d0]; f0.d[1] = b32[d0 + 1]; f0.d[2] = b32[d0 + 2]; f0.d[3] = b32[d0 + 3];
      f1.d[0] = b32[d1]; f1.d[1] = b32[d1 + 1]; f1.d[2] = b32[d1 + 2]; f1.d[3] = b32[d1 + 3];
      f32x4 acc = {0.f, 0.f, 0.f, 0.f};
      acc = __builtin_amdgcn_mfma_f32_16x16x32_bf16(aw0, f0.v, acc, 0, 0, 0);
      acc = __builtin_amdgcn_mfma_f32_16x16x32_bf16(aw1, f1.v, acc, 0, 0, 0);
      // acc[r]: D row q*4+r -> (q>>1)==0: conv(y0,oc=(q&1)*4+r); ==1: conv(y0+1,same oc)
      float pv[4];
#pragma unroll
      for (int r = 0; r < 4; ++r) {
        float vm = fmaxf(acc[r], __shfl_xor(acc[r], 32));   // vertical pool (q <-> q+2)
        float hp = fmaxf(vm, __shfl_xor(vm, 1));            // horizontal pool (c <-> c^1)
        pv[r] = fmaxf(hp + bias[r], 0.f);
      }
      if (q < 2 && (c & 1) == 0) {
        int px = (Xi * 16 + c) >> 1;
        unsigned short pk[4];
#pragma unroll
        for (int r = 0; r < 4; ++r) pk[r] = f2bf(pv[r]);
        unsigned int w0 = (unsigned int)pk[0] | ((unsigned int)pk[1] << 16);
        unsigned int w1 = (unsigned int)pk[2] | ((unsigned int)pk[3] << 16);
        *reinterpret_cast<uint2*>(p1u + (((Y + 2) * 36) + (px + 2)) * 8 + q * 4) =
            make_uint2(w0, w1);
      }
    }
  }
  __syncthreads();
}

__global__ __launch_bounds__(256) void simconv_kernel(
    const float* __restrict__ qf0, const float* __restrict__ qf1, const float* __restrict__ qf2,
    const float* __restrict__ cf0, const float* __restrict__ cf1, const float* __restrict__ cf2,
    const float* __restrict__ cb0, const float* __restrict__ cb1,
    const unsigned short* __restrict__ packA, const unsigned short* __restrict__ packW1,
    float* __restrict__ hcat)
{
  __shared__ __align__(16) unsigned short smem[20736];   // 41472 B -> 3 blocks/CU
  // lifetimes: qbf/cbf [0,9216) sim stage only;  p1u [0,10368) conv1->conv2 (after sim sync);
  //            cp0 [10368,15552) cp1 [15552,20736) sim->conv1
  unsigned short* qbf = smem;
  unsigned short* cbf = smem + 4608;
  unsigned short* p1u = smem;
  unsigned short* cp0 = smem + 10368;
  unsigned short* cp1 = smem + 15552;

  const int g = blockIdx.x, lvl = blockIdx.y, tid = threadIdx.x;

  if (lvl == 0)      sim_mfma<64>(qf0, cf0, qbf, cbf, cp0, cp1, g, tid);
  else if (lvl == 1) sim_mfma<32>(qf1, cf1, qbf, cbf, cp0, cp1, g, tid);
  else               sim_mfma<16>(qf2, cf2, qbf, cbf, cp0, cp1, g, tid);

  conv1_mfma(cp0, cp1, p1u, packW1, cb0, lvl, tid);

  // ---- conv2 via MFMA + in-register 2x2 pool -> hcat (no LDS round-trip) ----
  {
    const int lane = tid & 63, wave = tid >> 6;
    const int col = lane & 15, q = lane >> 4;

    s16x8 afr[7];
#pragma unroll
    for (int gg = 0; gg < 7; ++gg)
      afr[gg] = *reinterpret_cast<const s16x8*>(packA + ((size_t)(lvl * 7 + gg) * 64 + lane) * 8);

    int off[7];
#pragma unroll
    for (int gg = 0; gg < 7; ++gg) {
      int s = gg * 4 + q; if (s > 24) s = 24;
      off[gg] = (s / 5) * 288 + (s % 5) * 8;
    }
    float bias2[4];
#pragma unroll
    for (int r = 0; r < 4; ++r) bias2[r] = cb1[lvl * 16 + q * 4 + r];

    for (int pq = 0; pq < 4; ++pq) {
      const int py = wave * 4 + pq;                 // pooled row 0..15
#pragma unroll
      for (int h = 0; h < 2; ++h) {
        const int base0 = (2 * py) * 288 + h * 128 + col * 8;
        const int base1 = base0 + 288;
        f32x4 a0 = {0.f, 0.f, 0.f, 0.f}, a1 = {0.f, 0.f, 0.f, 0.f};
#pragma unroll
        for (int gg = 0; gg < 7; ++gg) {
          s16x8 b0 = *reinterpret_cast<const s16x8*>(p1u + base0 + off[gg]);
          a0 = __builtin_amdgcn_mfma_f32_16x16x32_bf16(afr[gg], b0, a0, 0, 0, 0);
          s16x8 b1 = *reinterpret_cast<const s16x8*>(p1u + base1 + off[gg]);
          a1 = __builtin_amdgcn_mfma_f32_16x16x32_bf16(afr[gg], b1, a1, 0, 0, 0);
        }
        float val[4];
#pragma unroll
        for (int r = 0; r < 4; ++r) {
          float vm = fmaxf(a0[r], a1[r]);                 // vertical pool (rows 2py,2py+1)
          float hp = fmaxf(vm, __shfl_xor(vm, 1));        // horizontal pool
          val[r] = fmaxf(hp + bias2[r], 0.f);
        }
        if ((col & 1) == 0) {
          int px = h * 8 + (col >> 1);
#pragma unroll
          for (int r = 0; r < 4; ++r)
            hcat[((size_t)g * 48 + lvl * 16 + q * 4 + r) * 256 + py * 16 + px] = val[r];
        }
      }
    }
  }
}

// ----------------------------- linear 0 via MFMA (unchanged, verified) -----------------------------
__global__ __launch_bounds__(256) void init_l0(const float* __restrict__ bl0, float* __restrict__ l0)
{
  int i = blockIdx.x * 256 + threadIdx.x;
  l0[i] = bl0[i & 255];
}

__global__ __launch_bounds__(256) void lin0_kernel(
    const float* __restrict__ A, const unsigned short* __restrict__ WT,
    float* __restrict__ l0)
{
  __shared__ __align__(16) unsigned short sAb[64 * 72];
  __shared__ __align__(16) unsigned short sBb[64 * 72];
  const int rb = blockIdx.x * 64;
  const int cb = blockIdx.y * 64;
  const int k0 = blockIdx.z * 768;
  const int tid = threadIdx.x;
  const int lane = tid & 63, wave = tid >> 6;
  const int wm = wave >> 1, wn = wave & 1;
  const int c = lane & 15, kg = lane >> 4;
  const int srow = tid >> 2;
  const int skq  = (tid & 3) * 16;

  f32x4 acc[2][2];
#pragma unroll
  for (int i = 0; i < 2; ++i)
#pragma unroll
    for (int j = 0; j < 2; ++j) acc[i][j] = (f32x4){0.f, 0.f, 0.f, 0.f};

  for (int kt = 0; kt < 768; kt += 64) {
    {
      const float* src = A + (size_t)(rb + srow) * 12288 + k0 + kt + skq;
      float4 v0 = *reinterpret_cast<const float4*>(src + 0);
      float4 v1 = *reinterpret_cast<const float4*>(src + 4);
      float4 v2 = *reinterpret_cast<const float4*>(src + 8);
      float4 v3 = *reinterpret_cast<const float4*>(src + 12);
      s16x8 p0, p1;
      p0[0] = (short)f2bf(v0.x); p0[1] = (short)f2bf(v0.y); p0[2] = (short)f2bf(v0.z); p0[3] = (short)f2bf(v0.w);
      p0[4] = (short)f2bf(v1.x); p0[5] = (short)f2bf(v1.y); p0[6] = (short)f2bf(v1.z); p0[7] = (short)f2bf(v1.w);
      p1[0] = (short)f2bf(v2.x); p1[1] = (short)f2bf(v2.y); p1[2] = (short)f2bf(v2.z); p1[3] = (short)f2bf(v2.w);
      p1[4] = (short)f2bf(v3.x); p1[5] = (short)f2bf(v3.y); p1[6] = (short)f2bf(v3.z); p1[7] = (short)f2bf(v3.w);
      *reinterpret_cast<s16x8*>(sAb + srow * 72 + skq)     = p0;
      *reinterpret_cast<s16x8*>(sAb + srow * 72 + skq + 8) = p1;
    }
    {
      const unsigned short* src = WT + (size_t)(cb + srow) * 12288 + k0 + kt + skq;
      s16x8 w0 = *reinterpret_cast<const s16x8*>(src);
      s16x8 w1 = *reinterpret_cast<const s16x8*>(src + 8);
      *reinterpret_cast<s16x8*>(sBb + srow * 72 + skq)     = w0;
      *reinterpret_cast<s16x8*>(sBb + srow * 72 + skq + 8) = w1;
    }
    __syncthreads();

#pragma unroll
    for (int kb = 0; kb < 64; kb += 32) {
      s16x8 a0 = *reinterpret_cast<const s16x8*>(sAb + (wm * 32 +  0 + c) * 72 + kb + kg * 8);
      s16x8 a1 = *reinterpret_cast<const s16x8*>(sAb + (wm * 32 + 16 + c) * 72 + kb + kg * 8);
      s16x8 b0 = *reinterpret_cast<const s16x8*>(sBb + (wn * 32 +  0 + c) * 72 + kb + kg * 8);
      s16x8 b1 = *reinterpret_cast<const s16x8*>(sBb + (wn * 32 + 16 + c) * 72 + kb + kg * 8);
      acc[0][0] = __builtin_amdgcn_mfma_f32_16x16x32_bf16(a0, b0, acc[0][0], 0, 0, 0);
      acc[0][1] = __builtin_amdgcn_mfma_f32_16x16x32_bf16(a0, b1, acc[0][1], 0, 0, 0);
      acc[1][0] = __builtin_amdgcn_mfma_f32_16x16x32_bf16(a1, b0, acc[1][0], 0, 0, 0);
      acc[1][1] = __builtin_amdgcn_mfma_f32_16x16x32_bf16(a1, b1, acc[1][1], 0, 0, 0);
    }
    __syncthreads();
  }

#pragma unroll
  for (int i = 0; i < 2; ++i)
#pragma unroll
    for (int j = 0; j < 2; ++j)
#pragma unroll
      for (int r = 0; r < 4; ++r) {
        int row = rb + wm * 32 + i * 16 + kg * 4 + r;
        int col = cb + wn * 32 + j * 16 + c;
        atomicAdd(&l0[(size_t)row * 256 + col], acc[i][j][r]);
      }
}

// ----------------------------- head -----------------------------
__global__ __launch_bounds__(64) void head_kernel(
    const float* __restrict__ l0, const float* __restrict__ Wl1, const float* __restrict__ bl1,
    const float* __restrict__ Wsc, const float* __restrict__ bsc, float* __restrict__ out)
{
  __shared__ float sr[256];
  const int b = blockIdx.x, j = threadIdx.x;
  for (int k = j; k < 256; k += 64) sr[k] = fmaxf(l0[(size_t)b * 256 + k], 0.f);
  __syncthreads();
  float acc = bl1[j];
  for (int k = 0; k < 256; ++k) acc = fmaf(sr[k], Wl1[k * 64 + j], acc);
  float v = fmaxf(acc, 0.f) * Wsc[j];
#pragma unroll
  for (int off = 32; off > 0; off >>= 1) v += __shfl_down(v, off);
  if (j == 0) out[b] = 1.f / (1.f + expf(-(v + bsc[0])));
}

// ----------------------------- launch -----------------------------
extern "C" void kernel_launch(void* const* d_in, const int* in_sizes, int n_in,
                              void* d_out, int out_size, void* d_ws, size_t ws_size,
                              hipStream_t stream)
{
  (void)in_sizes; (void)n_in; (void)out_size; (void)ws_size;
  const float* x_q = (const float*)d_in[0];
  const float* x_c = (const float*)d_in[1];
  const int*   src_q = (const int*)d_in[2];
  const int*   dst_q = (const int*)d_in[3];
  const int*   src_c = (const int*)d_in[4];
  const int*   dst_c = (const int*)d_in[5];
  const float* Wg0 = (const float*)d_in[6];
  const float* bg0 = (const float*)d_in[7];
  const float* Wg1 = (const float*)d_in[8];
  const float* bg1 = (const float*)d_in[9];
  const float* Wg2 = (const float*)d_in[10];
  const float* bg2 = (const float*)d_in[11];
  const float* cw0 = (const float*)d_in[12];
  const float* cb0 = (const float*)d_in[13];
  const float* cw1 = (const float*)d_in[14];
  const float* cb1 = (const float*)d_in[15];
  const float* Wl0 = (const float*)d_in[16];
  const float* bl0 = (const float*)d_in[17];
  const float* Wl1 = (const float*)d_in[18];
  const float* bl1 = (const float*)d_in[19];
  const float* Wsc = (const float*)d_in[20];
  const float* bsc = (const float*)d_in[21];
  float* out = (float*)d_out;

  float* ws = (float*)d_ws;
  float* qf0 = ws; ws += (size_t)NB * MM * 64;
  float* qf1 = ws; ws += (size_t)NB * MM * 32;
  float* qf2 = ws; ws += (size_t)NB * MM * 16;
  float* cf0 = ws; ws += (size_t)NB * MM * 64;
  float* cf1 = ws; ws += (size_t)NB * MM * 32;
  float* cf2 = ws; ws += (size_t)NB * MM * 16;
  float* hcat = ws; ws += (size_t)NB * 48 * 256;
  float* l0  = ws; ws += (size_t)NB * 256;
  unsigned short* packA  = (unsigned short*)ws; ws += 5376;   // 3*7*64*8 bf16
  unsigned short* packW1 = (unsigned short*)ws; ws += 1536;   // 3*2*64*8 bf16
  unsigned short* WT = (unsigned short*)ws; ws += (size_t)256 * 12288 / 2;

  pack_w<<<42, 256, 0, stream>>>(cw1, packA);
  pack_w1<<<12, 256, 0, stream>>>(cw0, packW1);
  pack_wl0<<<dim3(192, 4), 256, 0, stream>>>(Wl0, WT);

  gcn_kernel<<<dim3(NB, 2), 256, 0, stream>>>(x_q, x_c, src_q, dst_q, src_c, dst_c,
      Wg0, bg0, Wg1, bg1, Wg2, bg2, qf0, qf1, qf2, cf0, cf1, cf2);

  simconv_kernel<<<dim3(NB, 3), 256, 0, stream>>>(qf0, qf1, qf2, cf0, cf1, cf2,
      cb0, cb1, packA, packW1, hcat);

  init_l0<<<NB, 256, 0, stream>>>(bl0, l0);
  lin0_kernel<<<dim3(8, 4, 16), 256, 0, stream>>>(hcat, WT, l0);
  head_kernel<<<NB, 64, 0, stream>>>(l0, Wl1, bl1, Wsc, bsc, out);
}

// Round 9
// 119.910 us; speedup vs baseline: 1.6095x; 1.1576x over previous
//
#include <hip/hip_runtime.h>
#include <math.h>

#define NB 512      // graph pairs
#define MM 64       // nodes per graph
#define EPGc 512    // edges per graph

typedef __attribute__((ext_vector_type(8))) short s16x8;
typedef __attribute__((ext_vector_type(4))) float f32x4;

__device__ __forceinline__ unsigned short f2bf(float f) {
  union { float f; unsigned int u; } c; c.f = f;
  unsigned int u = c.u;
  return (unsigned short)((u + 0x7FFFu + ((u >> 16) & 1u)) >> 16);   // RNE
}
__device__ __forceinline__ float bf2f(unsigned short h) {
  union { unsigned int u; float f; } c; c.u = ((unsigned int)h) << 16;
  return c.f;
}
// ((hi:lo) >> sh) & 0xFFFFFFFF ; sh in {0,16} -> v_alignbit_b32
__device__ __forceinline__ unsigned int funnel16(unsigned int hi, unsigned int lo, unsigned int sh) {
  return (unsigned int)(((((unsigned long long)hi) << 32) | lo) >> sh);
}

// acc[j] += sum_kk a[kk] * b_kk[j]
__device__ __forceinline__ void fma4x4(float (&acc)[4], const float4 a,
    const float4 b0, const float4 b1, const float4 b2, const float4 b3)
{
  acc[0] = fmaf(a.x, b0.x, acc[0]); acc[0] = fmaf(a.y, b1.x, acc[0]);
  acc[0] = fmaf(a.z, b2.x, acc[0]); acc[0] = fmaf(a.w, b3.x, acc[0]);
  acc[1] = fmaf(a.x, b0.y, acc[1]); acc[1] = fmaf(a.y, b1.y, acc[1]);
  acc[1] = fmaf(a.z, b2.y, acc[1]); acc[1] = fmaf(a.w, b3.y, acc[1]);
  acc[2] = fmaf(a.x, b0.z, acc[2]); acc[2] = fmaf(a.y, b1.z, acc[2]);
  acc[2] = fmaf(a.z, b2.z, acc[2]); acc[2] = fmaf(a.w, b3.z, acc[2]);
  acc[3] = fmaf(a.x, b0.w, acc[3]); acc[3] = fmaf(a.y, b1.w, acc[3]);
  acc[3] = fmaf(a.z, b2.w, acc[3]); acc[3] = fmaf(a.w, b3.w, acc[3]);
}

// ----------------------------- GCN: dense-adjacency, register-tiled LDS GEMMs (bf16 feat output) --------
template<int Fin, int Fout, bool RELU>
__device__ __forceinline__ void gcn_layer(
    const float* __restrict__ W, const float* __restrict__ bias,
    const float* sA, float* sh, float* st, float* sW,
    unsigned short* __restrict__ outG, int g, int tid)
{
  constexpr int SIN = Fin + 4;
  constexpr int SOUT = Fout + 4;
  constexpr int TPR = Fout / 4;
  constexpr int TR  = (Fout == 64) ? 4 : (Fout == 32 ? 2 : 1);
  const int n0 = (tid / TPR) * TR;
  const int f0 = (tid % TPR) * 4;

  for (int i = tid; i < Fin * Fout / 4; i += 256)
    *reinterpret_cast<float4*>(sW + i * 4) = *reinterpret_cast<const float4*>(W + i * 4);
  __syncthreads();

  {
    float acc[TR][4];
#pragma unroll
    for (int i = 0; i < TR; ++i) { acc[i][0] = 0; acc[i][1] = 0; acc[i][2] = 0; acc[i][3] = 0; }
#pragma unroll
    for (int k = 0; k < Fin; k += 4) {
      float4 b0 = *reinterpret_cast<const float4*>(sW + (k + 0) * Fout + f0);
      float4 b1 = *reinterpret_cast<const float4*>(sW + (k + 1) * Fout + f0);
      float4 b2 = *reinterpret_cast<const float4*>(sW + (k + 2) * Fout + f0);
      float4 b3 = *reinterpret_cast<const float4*>(sW + (k + 3) * Fout + f0);
#pragma unroll
      for (int i = 0; i < TR; ++i) {
        float4 a = *reinterpret_cast<const float4*>(sh + (n0 + i) * SIN + k);
        fma4x4(acc[i], a, b0, b1, b2, b3);
      }
    }
#pragma unroll
    for (int i = 0; i < TR; ++i)
      *reinterpret_cast<float4*>(st + (n0 + i) * Fout + f0) =
          make_float4(acc[i][0], acc[i][1], acc[i][2], acc[i][3]);
  }
  __syncthreads();

  {
    float acc[TR][4];
#pragma unroll
    for (int i = 0; i < TR; ++i) { acc[i][0] = 0; acc[i][1] = 0; acc[i][2] = 0; acc[i][3] = 0; }
#pragma unroll
    for (int k = 0; k < 64; k += 4) {
      float4 b0 = *reinterpret_cast<const float4*>(st + (k + 0) * Fout + f0);
      float4 b1 = *reinterpret_cast<const float4*>(st + (k + 1) * Fout + f0);
      float4 b2 = *reinterpret_cast<const float4*>(st + (k + 2) * Fout + f0);
      float4 b3 = *reinterpret_cast<const float4*>(st + (k + 3) * Fout + f0);
#pragma unroll
      for (int i = 0; i < TR; ++i) {
        float4 a = *reinterpret_cast<const float4*>(sA + (n0 + i) * 68 + k);
        fma4x4(acc[i], a, b0, b1, b2, b3);
      }
    }
    float4 bv = *reinterpret_cast<const float4*>(bias + f0);
#pragma unroll
    for (int i = 0; i < TR; ++i) {
      float4 v = make_float4(acc[i][0] + bv.x, acc[i][1] + bv.y,
                             acc[i][2] + bv.z, acc[i][3] + bv.w);
      unsigned int w0 = (unsigned int)f2bf(v.x) | ((unsigned int)f2bf(v.y) << 16);
      unsigned int w1 = (unsigned int)f2bf(v.z) | ((unsigned int)f2bf(v.w) << 16);
      *reinterpret_cast<uint2*>(outG + (size_t)(g * MM + n0 + i) * Fout + f0) =
          make_uint2(w0, w1);
      float4 r = RELU ? make_float4(fmaxf(v.x, 0.f), fmaxf(v.y, 0.f),
                                    fmaxf(v.z, 0.f), fmaxf(v.w, 0.f)) : v;
      *reinterpret_cast<float4*>(sh + (n0 + i) * SOUT + f0) = r;
    }
  }
  __syncthreads();
}

__global__ __launch_bounds__(256) void gcn_kernel(
    const float* __restrict__ xq, const float* __restrict__ xc,
    const int* __restrict__ srcq, const int* __restrict__ dstq,
    const int* __restrict__ srcc, const int* __restrict__ dstc,
    const float* __restrict__ Wg0, const float* __restrict__ bg0,
    const float* __restrict__ Wg1, const float* __restrict__ bg1,
    const float* __restrict__ Wg2, const float* __restrict__ bg2,
    unsigned short* __restrict__ qf0, unsigned short* __restrict__ qf1,
    unsigned short* __restrict__ qf2, unsigned short* __restrict__ cf0,
    unsigned short* __restrict__ cf1, unsigned short* __restrict__ cf2)
{
  __shared__ __align__(16) float sA[64 * 68];
  __shared__ __align__(16) float sh[64 * 68];
  __shared__ __align__(16) float st[64 * 64];
  __shared__ __align__(16) float sW[2048];
  __shared__ float sDinv[MM];
  __shared__ int sDeg[MM];

  const int g = blockIdx.x;
  const int which = blockIdx.y;
  const float* x = which ? xc : xq;
  const int* src = which ? srcc : srcq;
  const int* dst = which ? dstc : dstq;
  unsigned short* f0p = which ? cf0 : qf0;
  unsigned short* f1p = which ? cf1 : qf1;
  unsigned short* f2p = which ? cf2 : qf2;
  const int tid = threadIdx.x;

  for (int i = tid; i < 64 * 68; i += 256) sA[i] = 0.f;
  if (tid < MM) sDeg[tid] = 1;
  __syncthreads();
  for (int e = tid; e < EPGc; e += 256)
    atomicAdd(&sDeg[dst[g * EPGc + e] - g * MM], 1);
  __syncthreads();
  if (tid < MM) sDinv[tid] = rsqrtf((float)sDeg[tid]);
  __syncthreads();
  for (int e = tid; e < EPGc; e += 256) {
    int s = src[g * EPGc + e] - g * MM;
    int d = dst[g * EPGc + e] - g * MM;
    atomicAdd(&sA[d * 68 + s], sDinv[s] * sDinv[d]);
  }
  if (tid < MM) atomicAdd(&sA[tid * 68 + tid], sDinv[tid] * sDinv[tid]);
  for (int i = tid; i < 512; i += 256) {
    float4 v = *reinterpret_cast<const float4*>(x + (size_t)g * 2048 + i * 4);
    int n = (i * 4) >> 5, k = (i * 4) & 31;
    *reinterpret_cast<float4*>(sh + n * 36 + k) = v;
  }
  __syncthreads();

  gcn_layer<32, 64, true >(Wg0, bg0, sA, sh, st, sW, f0p, g, tid);
  gcn_layer<64, 32, true >(Wg1, bg1, sA, sh, st, sW, f1p, g, tid);
  gcn_layer<32, 16, false>(Wg2, bg2, sA, sh, st, sW, f2p, g, tid);
}

// ----------------------------- merged prep: init_l0 + pack_w (conv2) + pack_w1 (conv1) -----------------
__global__ __launch_bounds__(256) void prep_misc(
    const float* __restrict__ cw1, const float* __restrict__ cw0,
    const float* __restrict__ bl0, unsigned short* __restrict__ packA,
    unsigned short* __restrict__ packW1, float* __restrict__ l0)
{
  const int b = blockIdx.x, t = threadIdx.x;
  if (b < 512) {                       // init_l0
    l0[b * 256 + t] = bl0[t];
    return;
  }
  if (b < 554) {                       // pack_w: conv2 A-frag
    int i = (b - 512) * 256 + t;
    if (i < 10752) {
      int j = i & 7, l = (i >> 3) & 63, g = (i >> 9) % 7, lvl = i / 3584;
      int oc = l & 15, sg = l >> 4;
      int s = g * 4 + sg;
      float v = 0.f;
      if (s < 25) v = cw1[((size_t)(lvl * 16 + oc) * 8 + j) * 25 + s];
      packA[i] = f2bf(v);
    }
    return;
  }
  {                                    // pack_w1: conv1 2-row A-frag
    int i = (b - 554) * 256 + t;
    if (i < 3072) {
      int j = i & 7, lane = (i >> 3) & 63, gg = (i >> 9) & 1, lvl = i >> 10;
      int m = lane & 15, q = lane >> 4;
      int u = gg * 4 + q;
      int oc = m & 7;
      int up = (m < 8) ? u : (u - 1);
      float v = 0.f;
      if (up >= 0 && up < 5 && j < 5)
        v = cw0[((size_t)(lvl * 8 + oc)) * 25 + up * 5 + j];
      packW1[i] = f2bf(v);
    }
  }
}

// ----------------------------- Wl0 prepack (unchanged) -----------------------------
__global__ __launch_bounds__(256) void pack_wl0(const float* __restrict__ Wl0,
                                                unsigned short* __restrict__ WT)
{
  __shared__ float tile[64][65];
  const int kb = blockIdx.x * 64;
  const int nb = blockIdx.y * 64;
  const int tid = threadIdx.x;
#pragma unroll
  for (int i = 0; i < 16; ++i) {
    int idx = i * 256 + tid, kk = idx >> 6, nn = idx & 63;
    tile[kk][nn] = Wl0[(size_t)(kb + kk) * 256 + nb + nn];
  }
  __syncthreads();
#pragma unroll
  for (int i = 0; i < 16; ++i) {
    int idx = i * 256 + tid, nn = idx >> 6, kk = idx & 63;
    WT[(size_t)(nb + nn) * 12288 + kb + kk] = f2bf(tile[kk][nn]);
  }
}

// ----------------------------- fused sim + conv1 + conv2 (single ssim copy, stride 80) ------------------
template<int F>
__device__ __forceinline__ void sim_mfma(const unsigned short* __restrict__ qf,
    const unsigned short* __restrict__ cf, unsigned short* qbf, unsigned short* cbf,
    unsigned short* cp, int g, int tid)
{
  constexpr int SQ = (F == 16) ? 40 : F + 8;
  // zero cp: 72*80 = 5760 u16 = 2880 u32
  {
    unsigned int* z = reinterpret_cast<unsigned int*>(cp);
    for (int i = tid; i < 2880; i += 256) z[i] = 0u;
  }
  // stage bf16 feats (pure copy, k-contiguous)
  for (int i = tid; i < 64 * F / 8; i += 256) {
    int row = (i * 8) / F, k = (i * 8) % F;
    s16x8 qv = *reinterpret_cast<const s16x8*>(qf + (size_t)g * 64 * F + i * 8);
    s16x8 cv = *reinterpret_cast<const s16x8*>(cf + (size_t)g * 64 * F + i * 8);
    *reinterpret_cast<s16x8*>(qbf + row * SQ + k) = qv;
    *reinterpret_cast<s16x8*>(cbf + row * SQ + k) = cv;
  }
  if (F == 16) {  // zero-pad k = 16..31
    for (int i = tid; i < 128; i += 256) {
      int row = i >> 1, h = (i & 1) * 8;
      s16x8 zz = {0, 0, 0, 0, 0, 0, 0, 0};
      *reinterpret_cast<s16x8*>(qbf + row * SQ + 16 + h) = zz;
      *reinterpret_cast<s16x8*>(cbf + row * SQ + 16 + h) = zz;
    }
  }
  __syncthreads();

  const int lane = tid & 63, wave = tid >> 6;
  const int c = lane & 15, q = lane >> 4;
  constexpr int NK = (F == 64) ? 2 : 1;

  f32x4 acc[4];
#pragma unroll
  for (int nt = 0; nt < 4; ++nt) acc[nt] = (f32x4){0.f, 0.f, 0.f, 0.f};
#pragma unroll
  for (int ks = 0; ks < NK; ++ks) {
    s16x8 af = *reinterpret_cast<const s16x8*>(qbf + (wave * 16 + c) * SQ + ks * 32 + q * 8);
#pragma unroll
    for (int nt = 0; nt < 4; ++nt) {
      s16x8 bf = *reinterpret_cast<const s16x8*>(cbf + (nt * 16 + c) * SQ + ks * 32 + q * 8);
      acc[nt] = __builtin_amdgcn_mfma_f32_16x16x32_bf16(af, bf, acc[nt], 0, 0, 0);
    }
  }
  // D: image row i = wave*16 + q*4 + r, image col n = nt*16 + c -> cp[(i+2)*80 + n+2]
#pragma unroll
  for (int nt = 0; nt < 4; ++nt)
#pragma unroll
    for (int r = 0; r < 4; ++r)
      cp[(wave * 16 + q * 4 + r + 2) * 80 + nt * 16 + c + 2] = f2bf(acc[nt][r]);
  __syncthreads();
}

// conv1 via MFMA: one B-fragment feeds 2 conv rows (A rows 0..7 -> y0, 8..15 -> y0+1).
// B-frag window [P, P+8) u16 assembled from 5 b32 + 4 alignbit (sh = (c&1)*16).
__device__ __forceinline__ void conv1_mfma(const unsigned short* cp,
    unsigned short* p1u, const unsigned short* __restrict__ packW1,
    const float* __restrict__ cb0, int lvl, int tid)
{
  const int lane = tid & 63, wave = tid >> 6;
  const int c = lane & 15, q = lane >> 4;

  // zero p1ci halo frame (272 cells, strided)
  for (int h = tid; h < 272; h += 256) {
    int r, cc;
    if (h < 72)       { r = h / 36;             cc = h % 36; }
    else if (h < 144) { r = 34 + (h - 72) / 36; cc = (h - 72) % 36; }
    else { int z = h - 144; r = 2 + (z >> 2); int wq = z & 3; cc = (wq < 2) ? wq : 32 + wq; }
    s16x8 zz = {0, 0, 0, 0, 0, 0, 0, 0};
    *reinterpret_cast<s16x8*>(p1u + (r * 36 + cc) * 8) = zz;
  }

  s16x8 aw0 = *reinterpret_cast<const s16x8*>(packW1 + ((size_t)(lvl * 2 + 0) * 64 + lane) * 8);
  s16x8 aw1 = *reinterpret_cast<const s16x8*>(packW1 + ((size_t)(lvl * 2 + 1) * 64 + lane) * 8);
  float bias[4];
#pragma unroll
  for (int r = 0; r < 4; ++r) bias[r] = cb0[lvl * 8 + (q & 1) * 4 + r];

  const unsigned int* b32 = reinterpret_cast<const unsigned int*>(cp);
  const unsigned int sh = (c & 1) * 16;
  const int dcol = (c >> 1);   // dword col base within row

  for (int pp = 0; pp < 8; ++pp) {
    const int Y = wave * 8 + pp;          // pooled row
    const int y0 = 2 * Y;
    const int R0 = (y0 + q) * 40;         // dword row base, gg0 (taps u=q)
    const int R1 = (y0 + 4 + q) * 40;     // gg1 (taps u=4+q)
#pragma unroll
    for (int Xi = 0; Xi < 4; ++Xi) {
      const int D0 = R0 + Xi * 8 + dcol;
      const int D1 = R1 + Xi * 8 + dcol;
      unsigned int d0[5], d1[5];
#pragma unroll
      for (int k = 0; k < 5; ++k) { d0[k] = b32[D0 + k]; d1[k] = b32[D1 + k]; }
      union { unsigned int w[4]; s16x8 v; } f0, f1;
#pragma unroll
      for (int k = 0; k < 4; ++k) {
        f0.w[k] = funnel16(d0[k + 1], d0[k], sh);
        f1.w[k] = funnel16(d1[k + 1], d1[k], sh);
      }
      f32x4 acc = {0.f, 0.f, 0.f, 0.f};
      acc = __builtin_amdgcn_mfma_f32_16x16x32_bf16(aw0, f0.v, acc, 0, 0, 0);
      acc = __builtin_amdgcn_mfma_f32_16x16x32_bf16(aw1, f1.v, acc, 0, 0, 0);
      // pool: ALL lanes compute (shuffles must be convergent); only q<2, even c store
      float pv[4];
#pragma unroll
      for (int r = 0; r < 4; ++r) {
        float vm = fmaxf(acc[r], __shfl_xor(acc[r], 32));   // vertical pool (q <-> q+2)
        float hp = fmaxf(vm, __shfl_xor(vm, 1));            // horizontal pool (c <-> c^1)
        pv[r] = fmaxf(hp + bias[r], 0.f);
      }
      if (q < 2 && (c & 1) == 0) {
        int px = (Xi * 16 + c) >> 1;
        unsigned short pk[4];
#pragma unroll
        for (int r = 0; r < 4; ++r) pk[r] = f2bf(pv[r]);
        unsigned int w0 = (unsigned int)pk[0] | ((unsigned int)pk[1] << 16);
        unsigned int w1 = (unsigned int)pk[2] | ((unsigned int)pk[3] << 16);
        *reinterpret_cast<uint2*>(p1u + (((Y + 2) * 36) + (px + 2)) * 8 + q * 4) =
            make_uint2(w0, w1);
      }
    }
  }
  __syncthreads();
}

__global__ __launch_bounds__(256) void simconv_kernel(
    const unsigned short* __restrict__ qf0, const unsigned short* __restrict__ qf1,
    const unsigned short* __restrict__ qf2, const unsigned short* __restrict__ cf0,
    const unsigned short* __restrict__ cf1, const unsigned short* __restrict__ cf2,
    const float* __restrict__ cb0, const float* __restrict__ cb1,
    const unsigned short* __restrict__ packA, const unsigned short* __restrict__ packW1,
    unsigned short* __restrict__ hcat)
{
  __shared__ __align__(16) unsigned short smem[16128];   // 32256 B -> 4 blocks/CU
  // lifetimes: qbf/cbf [0,9216) sim stage only;  p1u [0,10368) conv1->conv2 (after sim barrier);
  //            cp [10368,16128) = 72x80 sim->conv1
  unsigned short* qbf = smem;
  unsigned short* cbf = smem + 4608;
  unsigned short* p1u = smem;
  unsigned short* cp  = smem + 10368;

  const int g = blockIdx.x, lvl = blockIdx.y, tid = threadIdx.x;

  if (lvl == 0)      sim_mfma<64>(qf0, cf0, qbf, cbf, cp, g, tid);
  else if (lvl == 1) sim_mfma<32>(qf1, cf1, qbf, cbf, cp, g, tid);
  else               sim_mfma<16>(qf2, cf2, qbf, cbf, cp, g, tid);

  conv1_mfma(cp, p1u, packW1, cb0, lvl, tid);

  // ---- conv2 via MFMA + in-register 2x2 pool -> bf16 hcat ----
  {
    const int lane = tid & 63, wave = tid >> 6;
    const int col = lane & 15, q = lane >> 4;

    s16x8 afr[7];
#pragma unroll
    for (int gg = 0; gg < 7; ++gg)
      afr[gg] = *reinterpret_cast<const s16x8*>(packA + ((size_t)(lvl * 7 + gg) * 64 + lane) * 8);

    int off[7];
#pragma unroll
    for (int gg = 0; gg < 7; ++gg) {
      int s = gg * 4 + q; if (s > 24) s = 24;
      off[gg] = (s / 5) * 288 + (s % 5) * 8;
    }
    float bias2[4];
#pragma unroll
    for (int r = 0; r < 4; ++r) bias2[r] = cb1[lvl * 16 + q * 4 + r];

    for (int pq = 0; pq < 4; ++pq) {
      const int py = wave * 4 + pq;                 // pooled row 0..15
#pragma unroll
      for (int h = 0; h < 2; ++h) {
        const int base0 = (2 * py) * 288 + h * 128 + col * 8;
        const int base1 = base0 + 288;
        f32x4 a0 = {0.f, 0.f, 0.f, 0.f}, a1 = {0.f, 0.f, 0.f, 0.f};
#pragma unroll
        for (int gg = 0; gg < 7; ++gg) {
          s16x8 b0 = *reinterpret_cast<const s16x8*>(p1u + base0 + off[gg]);
          a0 = __builtin_amdgcn_mfma_f32_16x16x32_bf16(afr[gg], b0, a0, 0, 0, 0);
          s16x8 b1 = *reinterpret_cast<const s16x8*>(p1u + base1 + off[gg]);
          a1 = __builtin_amdgcn_mfma_f32_16x16x32_bf16(afr[gg], b1, a1, 0, 0, 0);
        }
        // pool: ALL lanes compute (convergent shuffles); store predicated (R8 bug fix)
        float val[4];
#pragma unroll
        for (int r = 0; r < 4; ++r) {
          float vm = fmaxf(a0[r], a1[r]);                 // vertical pool (rows 2py,2py+1)
          float hp = fmaxf(vm, __shfl_xor(vm, 1));        // horizontal pool
          val[r] = fmaxf(hp + bias2[r], 0.f);
        }
        if ((col & 1) == 0) {
          int px = h * 8 + (col >> 1);
#pragma unroll
          for (int r = 0; r < 4; ++r)
            hcat[((size_t)g * 48 + lvl * 16 + q * 4 + r) * 256 + py * 16 + px] = f2bf(val[r]);
        }
      }
    }
  }
}

// ----------------------------- linear 0 via MFMA: bf16 hcat @ bf16 WT, split-K --------------------------
__global__ __launch_bounds__(256) void lin0_kernel(
    const unsigned short* __restrict__ A, const unsigned short* __restrict__ WT,
    float* __restrict__ l0)
{
  __shared__ __align__(16) unsigned short sAb[64 * 72];
  __shared__ __align__(16) unsigned short sBb[64 * 72];
  const int rb = blockIdx.x * 64;
  const int cb = blockIdx.y * 64;
  const int k0 = blockIdx.z * 768;
  const int tid = threadIdx.x;
  const int lane = tid & 63, wave = tid >> 6;
  const int wm = wave >> 1, wn = wave & 1;
  const int c = lane & 15, kg = lane >> 4;
  const int srow = tid >> 2;
  const int skq  = (tid & 3) * 16;

  f32x4 acc[2][2];
#pragma unroll
  for (int i = 0; i < 2; ++i)
#pragma unroll
    for (int j = 0; j < 2; ++j) acc[i][j] = (f32x4){0.f, 0.f, 0.f, 0.f};

  for (int kt = 0; kt < 768; kt += 64) {
    {
      const unsigned short* src = A + (size_t)(rb + srow) * 12288 + k0 + kt + skq;
      s16x8 a0 = *reinterpret_cast<const s16x8*>(src);
      s16x8 a1 = *reinterpret_cast<const s16x8*>(src + 8);
      *reinterpret_cast<s16x8*>(sAb + srow * 72 + skq)     = a0;
      *reinterpret_cast<s16x8*>(sAb + srow * 72 + skq + 8) = a1;
    }
    {
      const unsigned short* src = WT + (size_t)(cb + srow) * 12288 + k0 + kt + skq;
      s16x8 w0 = *reinterpret_cast<const s16x8*>(src);
      s16x8 w1 = *reinterpret_cast<const s16x8*>(src + 8);
      *reinterpret_cast<s16x8*>(sBb + srow * 72 + skq)     = w0;
      *reinterpret_cast<s16x8*>(sBb + srow * 72 + skq + 8) = w1;
    }
    __syncthreads();

#pragma unroll
    for (int kb = 0; kb < 64; kb += 32) {
      s16x8 a0 = *reinterpret_cast<const s16x8*>(sAb + (wm * 32 +  0 + c) * 72 + kb + kg * 8);
      s16x8 a1 = *reinterpret_cast<const s16x8*>(sAb + (wm * 32 + 16 + c) * 72 + kb + kg * 8);
      s16x8 b0 = *reinterpret_cast<const s16x8*>(sBb + (wn * 32 +  0 + c) * 72 + kb + kg * 8);
      s16x8 b1 = *reinterpret_cast<const s16x8*>(sBb + (wn * 32 + 16 + c) * 72 + kb + kg * 8);
      acc[0][0] = __builtin_amdgcn_mfma_f32_16x16x32_bf16(a0, b0, acc[0][0], 0, 0, 0);
      acc[0][1] = __builtin_amdgcn_mfma_f32_16x16x32_bf16(a0, b1, acc[0][1], 0, 0, 0);
      acc[1][0] = __builtin_amdgcn_mfma_f32_16x16x32_bf16(a1, b0, acc[1][0], 0, 0, 0);
      acc[1][1] = __builtin_amdgcn_mfma_f32_16x16x32_bf16(a1, b1, acc[1][1], 0, 0, 0);
    }
    __syncthreads();
  }

#pragma unroll
  for (int i = 0; i < 2; ++i)
#pragma unroll
    for (int j = 0; j < 2; ++j)
#pragma unroll
      for (int r = 0; r < 4; ++r) {
        int row = rb + wm * 32 + i * 16 + kg * 4 + r;
        int col = cb + wn * 32 + j * 16 + c;
        atomicAdd(&l0[(size_t)row * 256 + col], acc[i][j][r]);
      }
}

// ----------------------------- head -----------------------------
__global__ __launch_bounds__(64) void head_kernel(
    const float* __restrict__ l0, const float* __restrict__ Wl1, const float* __restrict__ bl1,
    const float* __restrict__ Wsc, const float* __restrict__ bsc, float* __restrict__ out)
{
  __shared__ float sr[256];
  const int b = blockIdx.x, j = threadIdx.x;
  for (int k = j; k < 256; k += 64) sr[k] = fmaxf(l0[(size_t)b * 256 + k], 0.f);
  __syncthreads();
  float acc = bl1[j];
  for (int k = 0; k < 256; ++k) acc = fmaf(sr[k], Wl1[k * 64 + j], acc);
  float v = fmaxf(acc, 0.f) * Wsc[j];
#pragma unroll
  for (int off = 32; off > 0; off >>= 1) v += __shfl_down(v, off);
  if (j == 0) out[b] = 1.f / (1.f + expf(-(v + bsc[0])));
}

// ----------------------------- launch -----------------------------
extern "C" void kernel_launch(void* const* d_in, const int* in_sizes, int n_in,
                              void* d_out, int out_size, void* d_ws, size_t ws_size,
                              hipStream_t stream)
{
  (void)in_sizes; (void)n_in; (void)out_size; (void)ws_size;
  const float* x_q = (const float*)d_in[0];
  const float* x_c = (const float*)d_in[1];
  const int*   src_q = (const int*)d_in[2];
  const int*   dst_q = (const int*)d_in[3];
  const int*   src_c = (const int*)d_in[4];
  const int*   dst_c = (const int*)d_in[5];
  const float* Wg0 = (const float*)d_in[6];
  const float* bg0 = (const float*)d_in[7];
  const float* Wg1 = (const float*)d_in[8];
  const float* bg1 = (const float*)d_in[9];
  const float* Wg2 = (const float*)d_in[10];
  const float* bg2 = (const float*)d_in[11];
  const float* cw0 = (const float*)d_in[12];
  const float* cb0 = (const float*)d_in[13];
  const float* cw1 = (const float*)d_in[14];
  const float* cb1 = (const float*)d_in[15];
  const float* Wl0 = (const float*)d_in[16];
  const float* bl0 = (const float*)d_in[17];
  const float* Wl1 = (const float*)d_in[18];
  const float* bl1 = (const float*)d_in[19];
  const float* Wsc = (const float*)d_in[20];
  const float* bsc = (const float*)d_in[21];
  float* out = (float*)d_out;

  // workspace carve (float-granular; all u16 regions even-sized)
  float* ws = (float*)d_ws;
  unsigned short* qf0 = (unsigned short*)ws; ws += (size_t)NB * MM * 64 / 2;
  unsigned short* qf1 = (unsigned short*)ws; ws += (size_t)NB * MM * 32 / 2;
  unsigned short* qf2 = (unsigned short*)ws; ws += (size_t)NB * MM * 16 / 2;
  unsigned short* cf0 = (unsigned short*)ws; ws += (size_t)NB * MM * 64 / 2;
  unsigned short* cf1 = (unsigned short*)ws; ws += (size_t)NB * MM * 32 / 2;
  unsigned short* cf2 = (unsigned short*)ws; ws += (size_t)NB * MM * 16 / 2;
  unsigned short* hcat = (unsigned short*)ws; ws += (size_t)NB * 48 * 256 / 2;
  float* l0  = ws; ws += (size_t)NB * 256;
  unsigned short* packA  = (unsigned short*)ws; ws += 5376;   // 10752 bf16
  unsigned short* packW1 = (unsigned short*)ws; ws += 1536;   // 3072 bf16
  unsigned short* WT = (unsigned short*)ws; ws += (size_t)256 * 12288 / 2;

  prep_misc<<<566, 256, 0, stream>>>(cw1, cw0, bl0, packA, packW1, l0);
  pack_wl0<<<dim3(192, 4), 256, 0, stream>>>(Wl0, WT);

  gcn_kernel<<<dim3(NB, 2), 256, 0, stream>>>(x_q, x_c, src_q, dst_q, src_c, dst_c,
      Wg0, bg0, Wg1, bg1, Wg2, bg2, qf0, qf1, qf2, cf0, cf1, cf2);

  simconv_kernel<<<dim3(NB, 3), 256, 0, stream>>>(qf0, qf1, qf2, cf0, cf1, cf2,
      cb0, cb1, packA, packW1, hcat);

  lin0_kernel<<<dim3(8, 4, 16), 256, 0, stream>>>(hcat, WT, l0);
  head_kernel<<<NB, 64, 0, stream>>>(l0, Wl1, bl1, Wsc, bsc, out);
}

// Round 11
// 106.622 us; speedup vs baseline: 1.8100x; 1.1246x over previous
//
#include <hip/hip_runtime.h>
#include <math.h>

#define NB 512      // graph pairs
#define MM 64       // nodes per graph
#define EPGc 512    // edges per graph

typedef __attribute__((ext_vector_type(8))) short s16x8;
typedef __attribute__((ext_vector_type(4))) float f32x4;

__device__ __forceinline__ unsigned short f2bf(float f) {
  union { float f; unsigned int u; } c; c.f = f;
  unsigned int u = c.u;
  return (unsigned short)((u + 0x7FFFu + ((u >> 16) & 1u)) >> 16);   // RNE
}
__device__ __forceinline__ float bf2f(unsigned short h) {
  union { unsigned int u; float f; } c; c.u = ((unsigned int)h) << 16;
  return c.f;
}

// acc[j] += sum_kk a[kk] * b_kk[j]
__device__ __forceinline__ void fma4x4(float (&acc)[4], const float4 a,
    const float4 b0, const float4 b1, const float4 b2, const float4 b3)
{
  acc[0] = fmaf(a.x, b0.x, acc[0]); acc[0] = fmaf(a.y, b1.x, acc[0]);
  acc[0] = fmaf(a.z, b2.x, acc[0]); acc[0] = fmaf(a.w, b3.x, acc[0]);
  acc[1] = fmaf(a.x, b0.y, acc[1]); acc[1] = fmaf(a.y, b1.y, acc[1]);
  acc[1] = fmaf(a.z, b2.y, acc[1]); acc[1] = fmaf(a.w, b3.y, acc[1]);
  acc[2] = fmaf(a.x, b0.z, acc[2]); acc[2] = fmaf(a.y, b1.z, acc[2]);
  acc[2] = fmaf(a.z, b2.z, acc[2]); acc[2] = fmaf(a.w, b3.z, acc[2]);
  acc[3] = fmaf(a.x, b0.w, acc[3]); acc[3] = fmaf(a.y, b1.w, acc[3]);
  acc[3] = fmaf(a.z, b2.w, acc[3]); acc[3] = fmaf(a.w, b3.w, acc[3]);
}

// ----------------------------- GCN: dense-adjacency, register-tiled LDS GEMMs (bf16 feat output) --------
template<int Fin, int Fout, bool RELU>
__device__ __forceinline__ void gcn_layer(
    const float* __restrict__ W, const float* __restrict__ bias,
    const float* sA, float* sh, float* st, float* sW,
    unsigned short* __restrict__ outG, int g, int tid)
{
  constexpr int SIN = Fin + 4;
  constexpr int SOUT = Fout + 4;
  constexpr int TPR = Fout / 4;
  constexpr int TR  = (Fout == 64) ? 4 : (Fout == 32 ? 2 : 1);
  const int n0 = (tid / TPR) * TR;
  const int f0 = (tid % TPR) * 4;

  for (int i = tid; i < Fin * Fout / 4; i += 256)
    *reinterpret_cast<float4*>(sW + i * 4) = *reinterpret_cast<const float4*>(W + i * 4);
  __syncthreads();

  {
    float acc[TR][4];
#pragma unroll
    for (int i = 0; i < TR; ++i) { acc[i][0] = 0; acc[i][1] = 0; acc[i][2] = 0; acc[i][3] = 0; }
#pragma unroll
    for (int k = 0; k < Fin; k += 4) {
      float4 b0 = *reinterpret_cast<const float4*>(sW + (k + 0) * Fout + f0);
      float4 b1 = *reinterpret_cast<const float4*>(sW + (k + 1) * Fout + f0);
      float4 b2 = *reinterpret_cast<const float4*>(sW + (k + 2) * Fout + f0);
      float4 b3 = *reinterpret_cast<const float4*>(sW + (k + 3) * Fout + f0);
#pragma unroll
      for (int i = 0; i < TR; ++i) {
        float4 a = *reinterpret_cast<const float4*>(sh + (n0 + i) * SIN + k);
        fma4x4(acc[i], a, b0, b1, b2, b3);
      }
    }
#pragma unroll
    for (int i = 0; i < TR; ++i)
      *reinterpret_cast<float4*>(st + (n0 + i) * Fout + f0) =
          make_float4(acc[i][0], acc[i][1], acc[i][2], acc[i][3]);
  }
  __syncthreads();

  {
    float acc[TR][4];
#pragma unroll
    for (int i = 0; i < TR; ++i) { acc[i][0] = 0; acc[i][1] = 0; acc[i][2] = 0; acc[i][3] = 0; }
#pragma unroll
    for (int k = 0; k < 64; k += 4) {
      float4 b0 = *reinterpret_cast<const float4*>(st + (k + 0) * Fout + f0);
      float4 b1 = *reinterpret_cast<const float4*>(st + (k + 1) * Fout + f0);
      float4 b2 = *reinterpret_cast<const float4*>(st + (k + 2) * Fout + f0);
      float4 b3 = *reinterpret_cast<const float4*>(st + (k + 3) * Fout + f0);
#pragma unroll
      for (int i = 0; i < TR; ++i) {
        float4 a = *reinterpret_cast<const float4*>(sA + (n0 + i) * 68 + k);
        fma4x4(acc[i], a, b0, b1, b2, b3);
      }
    }
    float4 bv = *reinterpret_cast<const float4*>(bias + f0);
#pragma unroll
    for (int i = 0; i < TR; ++i) {
      float4 v = make_float4(acc[i][0] + bv.x, acc[i][1] + bv.y,
                             acc[i][2] + bv.z, acc[i][3] + bv.w);
      unsigned int w0 = (unsigned int)f2bf(v.x) | ((unsigned int)f2bf(v.y) << 16);
      unsigned int w1 = (unsigned int)f2bf(v.z) | ((unsigned int)f2bf(v.w) << 16);
      *reinterpret_cast<uint2*>(outG + (size_t)(g * MM + n0 + i) * Fout + f0) =
          make_uint2(w0, w1);
      float4 r = RELU ? make_float4(fmaxf(v.x, 0.f), fmaxf(v.y, 0.f),
                                    fmaxf(v.z, 0.f), fmaxf(v.w, 0.f)) : v;
      *reinterpret_cast<float4*>(sh + (n0 + i) * SOUT + f0) = r;
    }
  }
  __syncthreads();
}

__global__ __launch_bounds__(256) void gcn_kernel(
    const float* __restrict__ xq, const float* __restrict__ xc,
    const int* __restrict__ srcq, const int* __restrict__ dstq,
    const int* __restrict__ srcc, const int* __restrict__ dstc,
    const float* __restrict__ Wg0, const float* __restrict__ bg0,
    const float* __restrict__ Wg1, const float* __restrict__ bg1,
    const float* __restrict__ Wg2, const float* __restrict__ bg2,
    unsigned short* __restrict__ qf0, unsigned short* __restrict__ qf1,
    unsigned short* __restrict__ qf2, unsigned short* __restrict__ cf0,
    unsigned short* __restrict__ cf1, unsigned short* __restrict__ cf2)
{
  __shared__ __align__(16) float sA[64 * 68];
  __shared__ __align__(16) float sh[64 * 68];
  __shared__ __align__(16) float st[64 * 64];
  __shared__ __align__(16) float sW[2048];
  __shared__ float sDinv[MM];
  __shared__ int sDeg[MM];

  const int g = blockIdx.x;
  const int which = blockIdx.y;
  const float* x = which ? xc : xq;
  const int* src = which ? srcc : srcq;
  const int* dst = which ? dstc : dstq;
  unsigned short* f0p = which ? cf0 : qf0;
  unsigned short* f1p = which ? cf1 : qf1;
  unsigned short* f2p = which ? cf2 : qf2;
  const int tid = threadIdx.x;

  for (int i = tid; i < 64 * 68; i += 256) sA[i] = 0.f;
  if (tid < MM) sDeg[tid] = 1;
  __syncthreads();
  for (int e = tid; e < EPGc; e += 256)
    atomicAdd(&sDeg[dst[g * EPGc + e] - g * MM], 1);
  __syncthreads();
  if (tid < MM) sDinv[tid] = rsqrtf((float)sDeg[tid]);
  __syncthreads();
  for (int e = tid; e < EPGc; e += 256) {
    int s = src[g * EPGc + e] - g * MM;
    int d = dst[g * EPGc + e] - g * MM;
    atomicAdd(&sA[d * 68 + s], sDinv[s] * sDinv[d]);
  }
  if (tid < MM) atomicAdd(&sA[tid * 68 + tid], sDinv[tid] * sDinv[tid]);
  for (int i = tid; i < 512; i += 256) {
    float4 v = *reinterpret_cast<const float4*>(x + (size_t)g * 2048 + i * 4);
    int n = (i * 4) >> 5, k = (i * 4) & 31;
    *reinterpret_cast<float4*>(sh + n * 36 + k) = v;
  }
  __syncthreads();

  gcn_layer<32, 64, true >(Wg0, bg0, sA, sh, st, sW, f0p, g, tid);
  gcn_layer<64, 32, true >(Wg1, bg1, sA, sh, st, sW, f1p, g, tid);
  gcn_layer<32, 16, false>(Wg2, bg2, sA, sh, st, sW, f2p, g, tid);
}

// ----------------------------- merged prep: init_l0 + pack_w (conv2) + pack_w1 (conv1 col-shift) --------
__global__ __launch_bounds__(256) void prep_misc(
    const float* __restrict__ cw1, const float* __restrict__ cw0,
    const float* __restrict__ bl0, unsigned short* __restrict__ packA,
    unsigned short* __restrict__ packW1, float* __restrict__ l0)
{
  const int b = blockIdx.x, t = threadIdx.x;
  if (b < 512) {                       // init_l0
    l0[b * 256 + t] = bl0[t];
    return;
  }
  if (b < 554) {                       // pack_w: conv2 A-frag
    int i = (b - 512) * 256 + t;
    if (i < 10752) {
      int j = i & 7, l = (i >> 3) & 63, g = (i >> 9) % 7, lvl = i / 3584;
      int oc = l & 15, sg = l >> 4;
      int s = g * 4 + sg;
      float v = 0.f;
      if (s < 25) v = cw1[((size_t)(lvl * 16 + oc) * 8 + j) * 25 + s];
      packA[i] = f2bf(v);
    }
    return;
  }
  {                                    // pack_w1: conv1 COL-SHIFT A-frag
    // rows m=0..7: oc=m, pixel x0 variant:  A[k=(u=gg*4+q, j)] = w[oc][u][j], j<5
    // rows m=8..15: oc=m-8, pixel x0+1:     A[k=(u, j)] = w[oc][u][j-1], 1<=j<=5
    int i = (b - 554) * 256 + t;
    if (i < 3072) {
      int j = i & 7, lane = (i >> 3) & 63, gg = (i >> 9) & 1, lvl = i >> 10;
      int m = lane & 15, q = lane >> 4;
      int u = gg * 4 + q;
      int oc = m & 7;
      float v = 0.f;
      if (u < 5) {
        if (m < 8) { if (j < 5) v = cw0[((size_t)(lvl * 8 + oc)) * 25 + u * 5 + j]; }
        else       { if (j >= 1 && j <= 5) v = cw0[((size_t)(lvl * 8 + oc)) * 25 + u * 5 + (j - 1)]; }
      }
      packW1[i] = f2bf(v);
    }
  }
}

// ----------------------------- Wl0 prepack (unchanged) -----------------------------
__global__ __launch_bounds__(256) void pack_wl0(const float* __restrict__ Wl0,
                                                unsigned short* __restrict__ WT)
{
  __shared__ float tile[64][65];
  const int kb = blockIdx.x * 64;
  const int nb = blockIdx.y * 64;
  const int tid = threadIdx.x;
#pragma unroll
  for (int i = 0; i < 16; ++i) {
    int idx = i * 256 + tid, kk = idx >> 6, nn = idx & 63;
    tile[kk][nn] = Wl0[(size_t)(kb + kk) * 256 + nb + nn];
  }
  __syncthreads();
#pragma unroll
  for (int i = 0; i < 16; ++i) {
    int idx = i * 256 + tid, nn = idx >> 6, kk = idx & 63;
    WT[(size_t)(nb + nn) * 12288 + kb + kk] = f2bf(tile[kk][nn]);
  }
}

// ----------------------------- fused sim + conv1 + conv2 (single ssim copy, stride 80) ------------------
template<int F>
__device__ __forceinline__ void sim_mfma(const unsigned short* __restrict__ qf,
    const unsigned short* __restrict__ cf, unsigned short* qbf, unsigned short* cbf,
    unsigned short* cp, int g, int tid)
{
  constexpr int SQ = (F == 16) ? 40 : F + 8;
  // zero cp: 72*80 = 5760 u16 = 2880 u32
  {
    unsigned int* z = reinterpret_cast<unsigned int*>(cp);
    for (int i = tid; i < 2880; i += 256) z[i] = 0u;
  }
  // stage bf16 feats (pure copy, k-contiguous)
  for (int i = tid; i < 64 * F / 8; i += 256) {
    int row = (i * 8) / F, k = (i * 8) % F;
    s16x8 qv = *reinterpret_cast<const s16x8*>(qf + (size_t)g * 64 * F + i * 8);
    s16x8 cv = *reinterpret_cast<const s16x8*>(cf + (size_t)g * 64 * F + i * 8);
    *reinterpret_cast<s16x8*>(qbf + row * SQ + k) = qv;
    *reinterpret_cast<s16x8*>(cbf + row * SQ + k) = cv;
  }
  if (F == 16) {  // zero-pad k = 16..31
    for (int i = tid; i < 128; i += 256) {
      int row = i >> 1, h = (i & 1) * 8;
      s16x8 zz = {0, 0, 0, 0, 0, 0, 0, 0};
      *reinterpret_cast<s16x8*>(qbf + row * SQ + 16 + h) = zz;
      *reinterpret_cast<s16x8*>(cbf + row * SQ + 16 + h) = zz;
    }
  }
  __syncthreads();

  const int lane = tid & 63, wave = tid >> 6;
  const int c = lane & 15, q = lane >> 4;
  constexpr int NK = (F == 64) ? 2 : 1;

  f32x4 acc[4];
#pragma unroll
  for (int nt = 0; nt < 4; ++nt) acc[nt] = (f32x4){0.f, 0.f, 0.f, 0.f};
#pragma unroll
  for (int ks = 0; ks < NK; ++ks) {
    s16x8 af = *reinterpret_cast<const s16x8*>(qbf + (wave * 16 + c) * SQ + ks * 32 + q * 8);
#pragma unroll
    for (int nt = 0; nt < 4; ++nt) {
      s16x8 bf = *reinterpret_cast<const s16x8*>(cbf + (nt * 16 + c) * SQ + ks * 32 + q * 8);
      acc[nt] = __builtin_amdgcn_mfma_f32_16x16x32_bf16(af, bf, acc[nt], 0, 0, 0);
    }
  }
  // D: image row i = wave*16 + q*4 + r, image col n = nt*16 + c -> cp[(i+2)*80 + n+2]
#pragma unroll
  for (int nt = 0; nt < 4; ++nt)
#pragma unroll
    for (int r = 0; r < 4; ++r)
      cp[(wave * 16 + q * 4 + r + 2) * 80 + nt * 16 + c + 2] = f2bf(acc[nt][r]);
  __syncthreads();
}

// conv1 via MFMA, col-shift variant pair:
//   B lanes <-> EVEN pixels x0 = 2P (P = Xi*16 + c).
//   Padded coords: cp[r][p] = S(r-2, p-2); pixel x0 tap v touches padded col x0+v
//   -> window = padded u16 [2P, 2P+8) = 4 ALIGNED b32 at dword base P (R10 bug: P+1).
//   A rows 0..7 = oc (pixel x0), rows 8..15 = oc (pixel x0+1, taps shifted).
//   Vertical pool = register fmax (y0/y0+1 accumulators); horizontal = shfl_xor(32).
__device__ __forceinline__ void conv1_mfma(const unsigned short* cp,
    unsigned short* p1u, const unsigned short* __restrict__ packW1,
    const float* __restrict__ cb0, int lvl, int tid)
{
  const int lane = tid & 63, wave = tid >> 6;
  const int c = lane & 15, q = lane >> 4;

  // zero p1ci halo frame (272 cells, strided)
  for (int h = tid; h < 272; h += 256) {
    int r, cc;
    if (h < 72)       { r = h / 36;             cc = h % 36; }
    else if (h < 144) { r = 34 + (h - 72) / 36; cc = (h - 72) % 36; }
    else { int z = h - 144; r = 2 + (z >> 2); int wq = z & 3; cc = (wq < 2) ? wq : 32 + wq; }
    s16x8 zz = {0, 0, 0, 0, 0, 0, 0, 0};
    *reinterpret_cast<s16x8*>(p1u + (r * 36 + cc) * 8) = zz;
  }

  s16x8 aw0 = *reinterpret_cast<const s16x8*>(packW1 + ((size_t)(lvl * 2 + 0) * 64 + lane) * 8);
  s16x8 aw1 = *reinterpret_cast<const s16x8*>(packW1 + ((size_t)(lvl * 2 + 1) * 64 + lane) * 8);
  float bias[4];
#pragma unroll
  for (int r = 0; r < 4; ++r) bias[r] = cb0[lvl * 8 + (q & 1) * 4 + r];

  const unsigned int* b32 = reinterpret_cast<const unsigned int*>(cp);

  for (int pp = 0; pp < 8; ++pp) {
    const int Y = wave * 8 + pp;          // pooled row
    const int y0 = 2 * Y;
#pragma unroll
    for (int Xi = 0; Xi < 2; ++Xi) {
      const int P = Xi * 16 + c;          // pooled col; even pixel x0 = 2P
      const int col = P;                  // dword base = padded u16 2P / 2   (R10 fix)
      const int r00 = (y0 + q) * 40 + col;        // acc0 (row y0),   gg=0: u = q
      const int r01 = (y0 + 4 + q) * 40 + col;    // acc0,            gg=1: u = 4+q
      const int r10 = (y0 + 1 + q) * 40 + col;    // acc1 (row y0+1), gg=0
      const int r11 = (y0 + 5 + q) * 40 + col;    // acc1,            gg=1
      union { unsigned int w[4]; s16x8 v; } f00, f01, f10, f11;
#pragma unroll
      for (int k = 0; k < 4; ++k) {
        f00.w[k] = b32[r00 + k]; f01.w[k] = b32[r01 + k];
        f10.w[k] = b32[r10 + k]; f11.w[k] = b32[r11 + k];
      }
      f32x4 a0 = {0.f, 0.f, 0.f, 0.f}, a1 = {0.f, 0.f, 0.f, 0.f};
      a0 = __builtin_amdgcn_mfma_f32_16x16x32_bf16(aw0, f00.v, a0, 0, 0, 0);
      a0 = __builtin_amdgcn_mfma_f32_16x16x32_bf16(aw1, f01.v, a0, 0, 0, 0);
      a1 = __builtin_amdgcn_mfma_f32_16x16x32_bf16(aw0, f10.v, a1, 0, 0, 0);
      a1 = __builtin_amdgcn_mfma_f32_16x16x32_bf16(aw1, f11.v, a1, 0, 0, 0);
      // pool: ALL lanes compute (convergent shuffles); stores predicated
      float pv[4];
#pragma unroll
      for (int r = 0; r < 4; ++r) {
        float vm = fmaxf(a0[r], a1[r]);             // vertical pool (register)
        float hp = fmaxf(vm, __shfl_xor(vm, 32));   // horizontal pool (x <-> x+1)
        pv[r] = fmaxf(hp + bias[r], 0.f);
      }
      if (q < 2) {
        unsigned short pk[4];
#pragma unroll
        for (int r = 0; r < 4; ++r) pk[r] = f2bf(pv[r]);
        unsigned int w0 = (unsigned int)pk[0] | ((unsigned int)pk[1] << 16);
        unsigned int w1 = (unsigned int)pk[2] | ((unsigned int)pk[3] << 16);
        *reinterpret_cast<uint2*>(p1u + (((Y + 2) * 36) + (P + 2)) * 8 + q * 4) =
            make_uint2(w0, w1);
      }
    }
  }
  __syncthreads();
}

__global__ __launch_bounds__(256) void simconv_kernel(
    const unsigned short* __restrict__ qf0, const unsigned short* __restrict__ qf1,
    const unsigned short* __restrict__ qf2, const unsigned short* __restrict__ cf0,
    const unsigned short* __restrict__ cf1, const unsigned short* __restrict__ cf2,
    const float* __restrict__ cb0, const float* __restrict__ cb1,
    const unsigned short* __restrict__ packA, const unsigned short* __restrict__ packW1,
    unsigned short* __restrict__ hcat)
{
  __shared__ __align__(16) unsigned short smem[16128];   // 32256 B -> 5 blocks/CU
  // lifetimes: qbf/cbf [0,9216) sim stage only;  p1u [0,10368) conv1->conv2 (after sim barrier);
  //            cp [10368,16128) = 72x80 sim->conv1
  unsigned short* qbf = smem;
  unsigned short* cbf = smem + 4608;
  unsigned short* p1u = smem;
  unsigned short* cp  = smem + 10368;

  const int g = blockIdx.x, lvl = blockIdx.y, tid = threadIdx.x;

  if (lvl == 0)      sim_mfma<64>(qf0, cf0, qbf, cbf, cp, g, tid);
  else if (lvl == 1) sim_mfma<32>(qf1, cf1, qbf, cbf, cp, g, tid);
  else               sim_mfma<16>(qf2, cf2, qbf, cbf, cp, g, tid);

  conv1_mfma(cp, p1u, packW1, cb0, lvl, tid);

  // ---- conv2 via MFMA + in-register 2x2 pool -> bf16 hcat ----
  {
    const int lane = tid & 63, wave = tid >> 6;
    const int col = lane & 15, q = lane >> 4;

    s16x8 afr[7];
#pragma unroll
    for (int gg = 0; gg < 7; ++gg)
      afr[gg] = *reinterpret_cast<const s16x8*>(packA + ((size_t)(lvl * 7 + gg) * 64 + lane) * 8);

    int off[7];
#pragma unroll
    for (int gg = 0; gg < 7; ++gg) {
      int s = gg * 4 + q; if (s > 24) s = 24;
      off[gg] = (s / 5) * 288 + (s % 5) * 8;
    }
    float bias2[4];
#pragma unroll
    for (int r = 0; r < 4; ++r) bias2[r] = cb1[lvl * 16 + q * 4 + r];

    for (int pq = 0; pq < 4; ++pq) {
      const int py = wave * 4 + pq;                 // pooled row 0..15
#pragma unroll
      for (int h = 0; h < 2; ++h) {
        const int base0 = (2 * py) * 288 + h * 128 + col * 8;
        const int base1 = base0 + 288;
        f32x4 a0 = {0.f, 0.f, 0.f, 0.f}, a1 = {0.f, 0.f, 0.f, 0.f};
#pragma unroll
        for (int gg = 0; gg < 7; ++gg) {
          s16x8 b0 = *reinterpret_cast<const s16x8*>(p1u + base0 + off[gg]);
          a0 = __builtin_amdgcn_mfma_f32_16x16x32_bf16(afr[gg], b0, a0, 0, 0, 0);
          s16x8 b1 = *reinterpret_cast<const s16x8*>(p1u + base1 + off[gg]);
          a1 = __builtin_amdgcn_mfma_f32_16x16x32_bf16(afr[gg], b1, a1, 0, 0, 0);
        }
        // pool: ALL lanes compute (convergent shuffles); store predicated
        float val[4];
#pragma unroll
        for (int r = 0; r < 4; ++r) {
          float vm = fmaxf(a0[r], a1[r]);                 // vertical pool (rows 2py,2py+1)
          float hp = fmaxf(vm, __shfl_xor(vm, 1));        // horizontal pool
          val[r] = fmaxf(hp + bias2[r], 0.f);
        }
        if ((col & 1) == 0) {
          int px = h * 8 + (col >> 1);
#pragma unroll
          for (int r = 0; r < 4; ++r)
            hcat[((size_t)g * 48 + lvl * 16 + q * 4 + r) * 256 + py * 16 + px] = f2bf(val[r]);
        }
      }
    }
  }
}

// ----------------------------- linear 0 via MFMA: bf16 hcat @ bf16 WT, split-K --------------------------
__global__ __launch_bounds__(256) void lin0_kernel(
    const unsigned short* __restrict__ A, const unsigned short* __restrict__ WT,
    float* __restrict__ l0)
{
  __shared__ __align__(16) unsigned short sAb[64 * 72];
  __shared__ __align__(16) unsigned short sBb[64 * 72];
  const int rb = blockIdx.x * 64;
  const int cb = blockIdx.y * 64;
  const int k0 = blockIdx.z * 768;
  const int tid = threadIdx.x;
  const int lane = tid & 63, wave = tid >> 6;
  const int wm = wave >> 1, wn = wave & 1;
  const int c = lane & 15, kg = lane >> 4;
  const int srow = tid >> 2;
  const int skq  = (tid & 3) * 16;

  f32x4 acc[2][2];
#pragma unroll
  for (int i = 0; i < 2; ++i)
#pragma unroll
    for (int j = 0; j < 2; ++j) acc[i][j] = (f32x4){0.f, 0.f, 0.f, 0.f};

  for (int kt = 0; kt < 768; kt += 64) {
    {
      const unsigned short* src = A + (size_t)(rb + srow) * 12288 + k0 + kt + skq;
      s16x8 a0 = *reinterpret_cast<const s16x8*>(src);
      s16x8 a1 = *reinterpret_cast<const s16x8*>(src + 8);
      *reinterpret_cast<s16x8*>(sAb + srow * 72 + skq)     = a0;
      *reinterpret_cast<s16x8*>(sAb + srow * 72 + skq + 8) = a1;
    }
    {
      const unsigned short* src = WT + (size_t)(cb + srow) * 12288 + k0 + kt + skq;
      s16x8 w0 = *reinterpret_cast<const s16x8*>(src);
      s16x8 w1 = *reinterpret_cast<const s16x8*>(src + 8);
      *reinterpret_cast<s16x8*>(sBb + srow * 72 + skq)     = w0;
      *reinterpret_cast<s16x8*>(sBb + srow * 72 + skq + 8) = w1;
    }
    __syncthreads();

#pragma unroll
    for (int kb = 0; kb < 64; kb += 32) {
      s16x8 a0 = *reinterpret_cast<const s16x8*>(sAb + (wm * 32 +  0 + c) * 72 + kb + kg * 8);
      s16x8 a1 = *reinterpret_cast<const s16x8*>(sAb + (wm * 32 + 16 + c) * 72 + kb + kg * 8);
      s16x8 b0 = *reinterpret_cast<const s16x8*>(sBb + (wn * 32 +  0 + c) * 72 + kb + kg * 8);
      s16x8 b1 = *reinterpret_cast<const s16x8*>(sBb + (wn * 32 + 16 + c) * 72 + kb + kg * 8);
      acc[0][0] = __builtin_amdgcn_mfma_f32_16x16x32_bf16(a0, b0, acc[0][0], 0, 0, 0);
      acc[0][1] = __builtin_amdgcn_mfma_f32_16x16x32_bf16(a0, b1, acc[0][1], 0, 0, 0);
      acc[1][0] = __builtin_amdgcn_mfma_f32_16x16x32_bf16(a1, b0, acc[1][0], 0, 0, 0);
      acc[1][1] = __builtin_amdgcn_mfma_f32_16x16x32_bf16(a1, b1, acc[1][1], 0, 0, 0);
    }
    __syncthreads();
  }

#pragma unroll
  for (int i = 0; i < 2; ++i)
#pragma unroll
    for (int j = 0; j < 2; ++j)
#pragma unroll
      for (int r = 0; r < 4; ++r) {
        int row = rb + wm * 32 + i * 16 + kg * 4 + r;
        int col = cb + wn * 32 + j * 16 + c;
        atomicAdd(&l0[(size_t)row * 256 + col], acc[i][j][r]);
      }
}

// ----------------------------- head -----------------------------
__global__ __launch_bounds__(64) void head_kernel(
    const float* __restrict__ l0, const float* __restrict__ Wl1, const float* __restrict__ bl1,
    const float* __restrict__ Wsc, const float* __restrict__ bsc, float* __restrict__ out)
{
  __shared__ float sr[256];
  const int b = blockIdx.x, j = threadIdx.x;
  for (int k = j; k < 256; k += 64) sr[k] = fmaxf(l0[(size_t)b * 256 + k], 0.f);
  __syncthreads();
  float acc = bl1[j];
  for (int k = 0; k < 256; ++k) acc = fmaf(sr[k], Wl1[k * 64 + j], acc);
  float v = fmaxf(acc, 0.f) * Wsc[j];
#pragma unroll
  for (int off = 32; off > 0; off >>= 1) v += __shfl_down(v, off);
  if (j == 0) out[b] = 1.f / (1.f + expf(-(v + bsc[0])));
}

// ----------------------------- launch -----------------------------
extern "C" void kernel_launch(void* const* d_in, const int* in_sizes, int n_in,
                              void* d_out, int out_size, void* d_ws, size_t ws_size,
                              hipStream_t stream)
{
  (void)in_sizes; (void)n_in; (void)out_size; (void)ws_size;
  const float* x_q = (const float*)d_in[0];
  const float* x_c = (const float*)d_in[1];
  const int*   src_q = (const int*)d_in[2];
  const int*   dst_q = (const int*)d_in[3];
  const int*   src_c = (const int*)d_in[4];
  const int*   dst_c = (const int*)d_in[5];
  const float* Wg0 = (const float*)d_in[6];
  const float* bg0 = (const float*)d_in[7];
  const float* Wg1 = (const float*)d_in[8];
  const float* bg1 = (const float*)d_in[9];
  const float* Wg2 = (const float*)d_in[10];
  const float* bg2 = (const float*)d_in[11];
  const float* cw0 = (const float*)d_in[12];
  const float* cb0 = (const float*)d_in[13];
  const float* cw1 = (const float*)d_in[14];
  const float* cb1 = (const float*)d_in[15];
  const float* Wl0 = (const float*)d_in[16];
  const float* bl0 = (const float*)d_in[17];
  const float* Wl1 = (const float*)d_in[18];
  const float* bl1 = (const float*)d_in[19];
  const float* Wsc = (const float*)d_in[20];
  const float* bsc = (const float*)d_in[21];
  float* out = (float*)d_out;

  // workspace carve (float-granular; all u16 regions even-sized)
  float* ws = (float*)d_ws;
  unsigned short* qf0 = (unsigned short*)ws; ws += (size_t)NB * MM * 64 / 2;
  unsigned short* qf1 = (unsigned short*)ws; ws += (size_t)NB * MM * 32 / 2;
  unsigned short* qf2 = (unsigned short*)ws; ws += (size_t)NB * MM * 16 / 2;
  unsigned short* cf0 = (unsigned short*)ws; ws += (size_t)NB * MM * 64 / 2;
  unsigned short* cf1 = (unsigned short*)ws; ws += (size_t)NB * MM * 32 / 2;
  unsigned short* cf2 = (unsigned short*)ws; ws += (size_t)NB * MM * 16 / 2;
  unsigned short* hcat = (unsigned short*)ws; ws += (size_t)NB * 48 * 256 / 2;
  float* l0  = ws; ws += (size_t)NB * 256;
  unsigned short* packA  = (unsigned short*)ws; ws += 5376;   // 10752 bf16
  unsigned short* packW1 = (unsigned short*)ws; ws += 1536;   // 3072 bf16
  unsigned short* WT = (unsigned short*)ws; ws += (size_t)256 * 12288 / 2;

  prep_misc<<<566, 256, 0, stream>>>(cw1, cw0, bl0, packA, packW1, l0);
  pack_wl0<<<dim3(192, 4), 256, 0, stream>>>(Wl0, WT);

  gcn_kernel<<<dim3(NB, 2), 256, 0, stream>>>(x_q, x_c, src_q, dst_q, src_c, dst_c,
      Wg0, bg0, Wg1, bg1, Wg2, bg2, qf0, qf1, qf2, cf0, cf1, cf2);

  simconv_kernel<<<dim3(NB, 3), 256, 0, stream>>>(qf0, qf1, qf2, cf0, cf1, cf2,
      cb0, cb1, packA, packW1, hcat);

  lin0_kernel<<<dim3(8, 4, 16), 256, 0, stream>>>(hcat, WT, l0);
  head_kernel<<<NB, 64, 0, stream>>>(l0, Wl1, bl1, Wsc, bsc, out);
}

// Round 12
// 87.754 us; speedup vs baseline: 2.1992x; 1.2150x over previous
//
#include <hip/hip_runtime.h>
#include <math.h>

#define NB 512      // graph pairs
#define MM 64       // nodes per graph
#define EPGc 512    // edges per graph

typedef __attribute__((ext_vector_type(8))) short s16x8;
typedef __attribute__((ext_vector_type(4))) float f32x4;

__device__ __forceinline__ unsigned short f2bf(float f) {
  union { float f; unsigned int u; } c; c.f = f;
  unsigned int u = c.u;
  return (unsigned short)((u + 0x7FFFu + ((u >> 16) & 1u)) >> 16);   // RNE
}
__device__ __forceinline__ float bf2f(unsigned short h) {
  union { unsigned int u; float f; } c; c.u = ((unsigned int)h) << 16;
  return c.f;
}

// ----------------------------- GCN via MFMA ------------------------------------------------------------
// Layer = two GEMMs, both with natural MFMA operand layouts:
//   GEMM1: st = h @ W        A = h[node][fin] (LDS), B = WT[fout][fin] (global, L2-hot)
//          D(col=fout c, rows=node q*4+r) -> stT[fout][node] uint2 pack
//   GEMM2: outT = stT "@" A_hat : out[f][dst] = sum_src st[src][f] * A[dst][src]
//          A = stT[f][src] (LDS), B = Ab[dst][src] (LDS)
//          D(col=dst node, rows=feat) -> global feats[node][feat] + next-layer h, uint2 packs
template<int Fin, int Fout, bool RELU>
__device__ __forceinline__ void gcn_layer_mfma(
    const unsigned short* __restrict__ WT, const float* __restrict__ bias,
    unsigned short* hbuf, unsigned short* stT, const unsigned short* Ab,
    unsigned short* __restrict__ outG, int g, int tid)
{
  const int lane = tid & 63, w = tid >> 6;
  const int c = lane & 15, q = lane >> 4;
  constexpr int NT = Fout / 16;
  constexpr int KS = Fin / 32;

  // GEMM1: m-tile = w (nodes), n-tiles 0..NT-1 (fout)
#pragma unroll
  for (int nt = 0; nt < NT; ++nt) {
    f32x4 acc = {0.f, 0.f, 0.f, 0.f};
#pragma unroll
    for (int ks = 0; ks < KS; ++ks) {
      s16x8 a = *reinterpret_cast<const s16x8*>(hbuf + (w * 16 + c) * 72 + ks * 32 + q * 8);
      s16x8 b = *reinterpret_cast<const s16x8*>(WT + (nt * 16 + c) * Fin + ks * 32 + q * 8);
      acc = __builtin_amdgcn_mfma_f32_16x16x32_bf16(a, b, acc, 0, 0, 0);
    }
    // D: f = nt*16+c, node m = w*16+q*4+r -> stT[f][m], 4 consecutive m
    unsigned int w0 = (unsigned int)f2bf(acc[0]) | ((unsigned int)f2bf(acc[1]) << 16);
    unsigned int w1 = (unsigned int)f2bf(acc[2]) | ((unsigned int)f2bf(acc[3]) << 16);
    *reinterpret_cast<uint2*>(stT + (nt * 16 + c) * 72 + w * 16 + q * 4) = make_uint2(w0, w1);
  }
  __syncthreads();

  // GEMM2: n-tile = w (dst nodes), m-tiles 0..NT-1 (feats), K = 64 src nodes
#pragma unroll
  for (int mt = 0; mt < NT; ++mt) {
    f32x4 acc = {0.f, 0.f, 0.f, 0.f};
#pragma unroll
    for (int ks = 0; ks < 2; ++ks) {
      s16x8 a = *reinterpret_cast<const s16x8*>(stT + (mt * 16 + c) * 72 + ks * 32 + q * 8);
      s16x8 b = *reinterpret_cast<const s16x8*>(Ab + (w * 16 + c) * 72 + ks * 32 + q * 8);
      acc = __builtin_amdgcn_mfma_f32_16x16x32_bf16(a, b, acc, 0, 0, 0);
    }
    const int node = w * 16 + c, f0 = mt * 16 + q * 4;
    unsigned short pk[4], pr[4];
#pragma unroll
    for (int r = 0; r < 4; ++r) {
      float v = acc[r] + bias[f0 + r];
      pk[r] = f2bf(v);
      pr[r] = f2bf(fmaxf(v, 0.f));
    }
    *reinterpret_cast<uint2*>(outG + (size_t)(g * MM + node) * Fout + f0) =
        make_uint2((unsigned int)pk[0] | ((unsigned int)pk[1] << 16),
                   (unsigned int)pk[2] | ((unsigned int)pk[3] << 16));
    if (RELU)
      *reinterpret_cast<uint2*>(hbuf + node * 72 + f0) =
          make_uint2((unsigned int)pr[0] | ((unsigned int)pr[1] << 16),
                     (unsigned int)pr[2] | ((unsigned int)pr[3] << 16));
  }
  __syncthreads();
}

__global__ __launch_bounds__(256) void gcn_kernel(
    const float* __restrict__ xq, const float* __restrict__ xc,
    const int* __restrict__ srcq, const int* __restrict__ dstq,
    const int* __restrict__ srcc, const int* __restrict__ dstc,
    const unsigned short* __restrict__ WgT,   // [0,2048) L0 64x32; [2048,4096) L1 32x64; [4096,4608) L2 16x32
    const float* __restrict__ bg0, const float* __restrict__ bg1, const float* __restrict__ bg2,
    unsigned short* __restrict__ qf0, unsigned short* __restrict__ qf1,
    unsigned short* __restrict__ qf2, unsigned short* __restrict__ cf0,
    unsigned short* __restrict__ cf1, unsigned short* __restrict__ cf2)
{
  __shared__ __align__(16) unsigned short smem[13824];  // 27648 B: hbuf|stT|Ab, each [64][72]
  __shared__ float sDinv[MM];
  __shared__ int sDeg[MM];
  unsigned short* hbuf = smem;
  unsigned short* stT  = smem + 4608;
  unsigned short* Ab   = smem + 9216;
  float* sAf = reinterpret_cast<float*>(smem);   // [64][68] fp32 = 8704 u16, aliases hbuf+stT (build phase only)

  const int g = blockIdx.x;
  const int which = blockIdx.y;
  const float* x = which ? xc : xq;
  const int* src = which ? srcc : srcq;
  const int* dst = which ? dstc : dstq;
  unsigned short* f0p = which ? cf0 : qf0;
  unsigned short* f1p = which ? cf1 : qf1;
  unsigned short* f2p = which ? cf2 : qf2;
  const int tid = threadIdx.x;

  // ---- build normalized dense adjacency (fp32, LDS atomics) ----
  for (int i = tid; i < 64 * 68; i += 256) sAf[i] = 0.f;
  if (tid < MM) sDeg[tid] = 1;   // self loop
  __syncthreads();
  for (int e = tid; e < EPGc; e += 256)
    atomicAdd(&sDeg[dst[g * EPGc + e] - g * MM], 1);
  __syncthreads();
  if (tid < MM) sDinv[tid] = rsqrtf((float)sDeg[tid]);
  __syncthreads();
  for (int e = tid; e < EPGc; e += 256) {
    int s = src[g * EPGc + e] - g * MM;
    int d = dst[g * EPGc + e] - g * MM;
    atomicAdd(&sAf[d * 68 + s], sDinv[s] * sDinv[d]);
  }
  if (tid < MM) atomicAdd(&sAf[tid * 68 + tid], sDinv[tid] * sDinv[tid]);
  __syncthreads();
  // convert to bf16 Ab[dst][src], stride 72 (Ab region disjoint from sAf)
  for (int i = tid; i < 4096; i += 256) {
    int r = i >> 6, s = i & 63;
    Ab[r * 72 + s] = f2bf(sAf[r * 68 + s]);
  }
  __syncthreads();
  // stage x -> hbuf bf16 [node][feat], stride 72 (overwrites sAf region; Ab safe)
  {
    const float* xs = x + (size_t)g * 2048 + tid * 8;
    float4 v0 = *reinterpret_cast<const float4*>(xs);
    float4 v1 = *reinterpret_cast<const float4*>(xs + 4);
    s16x8 p;
    p[0] = (short)f2bf(v0.x); p[1] = (short)f2bf(v0.y); p[2] = (short)f2bf(v0.z); p[3] = (short)f2bf(v0.w);
    p[4] = (short)f2bf(v1.x); p[5] = (short)f2bf(v1.y); p[6] = (short)f2bf(v1.z); p[7] = (short)f2bf(v1.w);
    int node = tid >> 2, k = (tid & 3) * 8;
    *reinterpret_cast<s16x8*>(hbuf + node * 72 + k) = p;
  }
  __syncthreads();

  gcn_layer_mfma<32, 64, true >(WgT,        bg0, hbuf, stT, Ab, f0p, g, tid);
  gcn_layer_mfma<64, 32, true >(WgT + 2048, bg1, hbuf, stT, Ab, f1p, g, tid);
  gcn_layer_mfma<32, 16, false>(WgT + 4096, bg2, hbuf, stT, Ab, f2p, g, tid);
}

// ----------------------------- merged prep: init_l0 + pack_w + pack_w1 + pack WgT ----------------------
__global__ __launch_bounds__(256) void prep_misc(
    const float* __restrict__ cw1, const float* __restrict__ cw0,
    const float* __restrict__ bl0,
    const float* __restrict__ Wg0, const float* __restrict__ Wg1, const float* __restrict__ Wg2,
    unsigned short* __restrict__ packA, unsigned short* __restrict__ packW1,
    unsigned short* __restrict__ WgT, float* __restrict__ l0)
{
  const int b = blockIdx.x, t = threadIdx.x;
  if (b < 512) {                       // init_l0
    l0[b * 256 + t] = bl0[t];
    return;
  }
  if (b < 554) {                       // pack_w: conv2 A-frag
    int i = (b - 512) * 256 + t;
    if (i < 10752) {
      int j = i & 7, l = (i >> 3) & 63, g = (i >> 9) % 7, lvl = i / 3584;
      int oc = l & 15, sg = l >> 4;
      int s = g * 4 + sg;
      float v = 0.f;
      if (s < 25) v = cw1[((size_t)(lvl * 16 + oc) * 8 + j) * 25 + s];
      packA[i] = f2bf(v);
    }
    return;
  }
  if (b < 566) {                       // pack_w1: conv1 COL-SHIFT A-frag
    int i = (b - 554) * 256 + t;
    if (i < 3072) {
      int j = i & 7, lane = (i >> 3) & 63, gg = (i >> 9) & 1, lvl = i >> 10;
      int m = lane & 15, q = lane >> 4;
      int u = gg * 4 + q;
      int oc = m & 7;
      float v = 0.f;
      if (u < 5) {
        if (m < 8) { if (j < 5) v = cw0[((size_t)(lvl * 8 + oc)) * 25 + u * 5 + j]; }
        else       { if (j >= 1 && j <= 5) v = cw0[((size_t)(lvl * 8 + oc)) * 25 + u * 5 + (j - 1)]; }
      }
      packW1[i] = f2bf(v);
    }
    return;
  }
  {                                    // pack WgT: transposed bf16 GCN weights
    int i = (b - 566) * 256 + t;
    if (i < 2048) {                    // L0: WT0[n<64][k<32] = Wg0[k][n], Wg0 is (32,64)
      int n = i >> 5, k = i & 31;
      WgT[i] = f2bf(Wg0[k * 64 + n]);
    } else if (i < 4096) {             // L1: WT1[n<32][k<64] = Wg1[k][n], Wg1 is (64,32)
      int j = i - 2048, n = j >> 6, k = j & 63;
      WgT[i] = f2bf(Wg1[k * 32 + n]);
    } else if (i < 4608) {             // L2: WT2[n<16][k<32] = Wg2[k][n], Wg2 is (32,16)
      int j = i - 4096, n = j >> 5, k = j & 31;
      WgT[i] = f2bf(Wg2[k * 16 + n]);
    }
  }
}

// ----------------------------- Wl0 prepack (unchanged) -----------------------------
__global__ __launch_bounds__(256) void pack_wl0(const float* __restrict__ Wl0,
                                                unsigned short* __restrict__ WT)
{
  __shared__ float tile[64][65];
  const int kb = blockIdx.x * 64;
  const int nb = blockIdx.y * 64;
  const int tid = threadIdx.x;
#pragma unroll
  for (int i = 0; i < 16; ++i) {
    int idx = i * 256 + tid, kk = idx >> 6, nn = idx & 63;
    tile[kk][nn] = Wl0[(size_t)(kb + kk) * 256 + nb + nn];
  }
  __syncthreads();
#pragma unroll
  for (int i = 0; i < 16; ++i) {
    int idx = i * 256 + tid, nn = idx >> 6, kk = idx & 63;
    WT[(size_t)(nb + nn) * 12288 + kb + kk] = f2bf(tile[kk][nn]);
  }
}

// ----------------------------- fused sim + conv1 + conv2 (unchanged, verified R11) ----------------------
template<int F>
__device__ __forceinline__ void sim_mfma(const unsigned short* __restrict__ qf,
    const unsigned short* __restrict__ cf, unsigned short* qbf, unsigned short* cbf,
    unsigned short* cp, int g, int tid)
{
  constexpr int SQ = (F == 16) ? 40 : F + 8;
  {
    unsigned int* z = reinterpret_cast<unsigned int*>(cp);
    for (int i = tid; i < 2880; i += 256) z[i] = 0u;
  }
  for (int i = tid; i < 64 * F / 8; i += 256) {
    int row = (i * 8) / F, k = (i * 8) % F;
    s16x8 qv = *reinterpret_cast<const s16x8*>(qf + (size_t)g * 64 * F + i * 8);
    s16x8 cv = *reinterpret_cast<const s16x8*>(cf + (size_t)g * 64 * F + i * 8);
    *reinterpret_cast<s16x8*>(qbf + row * SQ + k) = qv;
    *reinterpret_cast<s16x8*>(cbf + row * SQ + k) = cv;
  }
  if (F == 16) {
    for (int i = tid; i < 128; i += 256) {
      int row = i >> 1, h = (i & 1) * 8;
      s16x8 zz = {0, 0, 0, 0, 0, 0, 0, 0};
      *reinterpret_cast<s16x8*>(qbf + row * SQ + 16 + h) = zz;
      *reinterpret_cast<s16x8*>(cbf + row * SQ + 16 + h) = zz;
    }
  }
  __syncthreads();

  const int lane = tid & 63, wave = tid >> 6;
  const int c = lane & 15, q = lane >> 4;
  constexpr int NK = (F == 64) ? 2 : 1;

  f32x4 acc[4];
#pragma unroll
  for (int nt = 0; nt < 4; ++nt) acc[nt] = (f32x4){0.f, 0.f, 0.f, 0.f};
#pragma unroll
  for (int ks = 0; ks < NK; ++ks) {
    s16x8 af = *reinterpret_cast<const s16x8*>(qbf + (wave * 16 + c) * SQ + ks * 32 + q * 8);
#pragma unroll
    for (int nt = 0; nt < 4; ++nt) {
      s16x8 bf = *reinterpret_cast<const s16x8*>(cbf + (nt * 16 + c) * SQ + ks * 32 + q * 8);
      acc[nt] = __builtin_amdgcn_mfma_f32_16x16x32_bf16(af, bf, acc[nt], 0, 0, 0);
    }
  }
#pragma unroll
  for (int nt = 0; nt < 4; ++nt)
#pragma unroll
    for (int r = 0; r < 4; ++r)
      cp[(wave * 16 + q * 4 + r + 2) * 80 + nt * 16 + c + 2] = f2bf(acc[nt][r]);
  __syncthreads();
}

__device__ __forceinline__ void conv1_mfma(const unsigned short* cp,
    unsigned short* p1u, const unsigned short* __restrict__ packW1,
    const float* __restrict__ cb0, int lvl, int tid)
{
  const int lane = tid & 63, wave = tid >> 6;
  const int c = lane & 15, q = lane >> 4;

  for (int h = tid; h < 272; h += 256) {
    int r, cc;
    if (h < 72)       { r = h / 36;             cc = h % 36; }
    else if (h < 144) { r = 34 + (h - 72) / 36; cc = (h - 72) % 36; }
    else { int z = h - 144; r = 2 + (z >> 2); int wq = z & 3; cc = (wq < 2) ? wq : 32 + wq; }
    s16x8 zz = {0, 0, 0, 0, 0, 0, 0, 0};
    *reinterpret_cast<s16x8*>(p1u + (r * 36 + cc) * 8) = zz;
  }

  s16x8 aw0 = *reinterpret_cast<const s16x8*>(packW1 + ((size_t)(lvl * 2 + 0) * 64 + lane) * 8);
  s16x8 aw1 = *reinterpret_cast<const s16x8*>(packW1 + ((size_t)(lvl * 2 + 1) * 64 + lane) * 8);
  float bias[4];
#pragma unroll
  for (int r = 0; r < 4; ++r) bias[r] = cb0[lvl * 8 + (q & 1) * 4 + r];

  const unsigned int* b32 = reinterpret_cast<const unsigned int*>(cp);

  for (int pp = 0; pp < 8; ++pp) {
    const int Y = wave * 8 + pp;
    const int y0 = 2 * Y;
#pragma unroll
    for (int Xi = 0; Xi < 2; ++Xi) {
      const int P = Xi * 16 + c;
      const int col = P;
      const int r00 = (y0 + q) * 40 + col;
      const int r01 = (y0 + 4 + q) * 40 + col;
      const int r10 = (y0 + 1 + q) * 40 + col;
      const int r11 = (y0 + 5 + q) * 40 + col;
      union { unsigned int w[4]; s16x8 v; } f00, f01, f10, f11;
#pragma unroll
      for (int k = 0; k < 4; ++k) {
        f00.w[k] = b32[r00 + k]; f01.w[k] = b32[r01 + k];
        f10.w[k] = b32[r10 + k]; f11.w[k] = b32[r11 + k];
      }
      f32x4 a0 = {0.f, 0.f, 0.f, 0.f}, a1 = {0.f, 0.f, 0.f, 0.f};
      a0 = __builtin_amdgcn_mfma_f32_16x16x32_bf16(aw0, f00.v, a0, 0, 0, 0);
      a0 = __builtin_amdgcn_mfma_f32_16x16x32_bf16(aw1, f01.v, a0, 0, 0, 0);
      a1 = __builtin_amdgcn_mfma_f32_16x16x32_bf16(aw0, f10.v, a1, 0, 0, 0);
      a1 = __builtin_amdgcn_mfma_f32_16x16x32_bf16(aw1, f11.v, a1, 0, 0, 0);
      float pv[4];
#pragma unroll
      for (int r = 0; r < 4; ++r) {
        float vm = fmaxf(a0[r], a1[r]);
        float hp = fmaxf(vm, __shfl_xor(vm, 32));
        pv[r] = fmaxf(hp + bias[r], 0.f);
      }
      if (q < 2) {
        unsigned short pk[4];
#pragma unroll
        for (int r = 0; r < 4; ++r) pk[r] = f2bf(pv[r]);
        unsigned int w0 = (unsigned int)pk[0] | ((unsigned int)pk[1] << 16);
        unsigned int w1 = (unsigned int)pk[2] | ((unsigned int)pk[3] << 16);
        *reinterpret_cast<uint2*>(p1u + (((Y + 2) * 36) + (P + 2)) * 8 + q * 4) =
            make_uint2(w0, w1);
      }
    }
  }
  __syncthreads();
}

__global__ __launch_bounds__(256) void simconv_kernel(
    const unsigned short* __restrict__ qf0, const unsigned short* __restrict__ qf1,
    const unsigned short* __restrict__ qf2, const unsigned short* __restrict__ cf0,
    const unsigned short* __restrict__ cf1, const unsigned short* __restrict__ cf2,
    const float* __restrict__ cb0, const float* __restrict__ cb1,
    const unsigned short* __restrict__ packA, const unsigned short* __restrict__ packW1,
    unsigned short* __restrict__ hcat)
{
  __shared__ __align__(16) unsigned short smem[16128];
  unsigned short* qbf = smem;
  unsigned short* cbf = smem + 4608;
  unsigned short* p1u = smem;
  unsigned short* cp  = smem + 10368;

  const int g = blockIdx.x, lvl = blockIdx.y, tid = threadIdx.x;

  if (lvl == 0)      sim_mfma<64>(qf0, cf0, qbf, cbf, cp, g, tid);
  else if (lvl == 1) sim_mfma<32>(qf1, cf1, qbf, cbf, cp, g, tid);
  else               sim_mfma<16>(qf2, cf2, qbf, cbf, cp, g, tid);

  conv1_mfma(cp, p1u, packW1, cb0, lvl, tid);

  {
    const int lane = tid & 63, wave = tid >> 6;
    const int col = lane & 15, q = lane >> 4;

    s16x8 afr[7];
#pragma unroll
    for (int gg = 0; gg < 7; ++gg)
      afr[gg] = *reinterpret_cast<const s16x8*>(packA + ((size_t)(lvl * 7 + gg) * 64 + lane) * 8);

    int off[7];
#pragma unroll
    for (int gg = 0; gg < 7; ++gg) {
      int s = gg * 4 + q; if (s > 24) s = 24;
      off[gg] = (s / 5) * 288 + (s % 5) * 8;
    }
    float bias2[4];
#pragma unroll
    for (int r = 0; r < 4; ++r) bias2[r] = cb1[lvl * 16 + q * 4 + r];

    for (int pq = 0; pq < 4; ++pq) {
      const int py = wave * 4 + pq;
#pragma unroll
      for (int h = 0; h < 2; ++h) {
        const int base0 = (2 * py) * 288 + h * 128 + col * 8;
        const int base1 = base0 + 288;
        f32x4 a0 = {0.f, 0.f, 0.f, 0.f}, a1 = {0.f, 0.f, 0.f, 0.f};
#pragma unroll
        for (int gg = 0; gg < 7; ++gg) {
          s16x8 b0 = *reinterpret_cast<const s16x8*>(p1u + base0 + off[gg]);
          a0 = __builtin_amdgcn_mfma_f32_16x16x32_bf16(afr[gg], b0, a0, 0, 0, 0);
          s16x8 b1 = *reinterpret_cast<const s16x8*>(p1u + base1 + off[gg]);
          a1 = __builtin_amdgcn_mfma_f32_16x16x32_bf16(afr[gg], b1, a1, 0, 0, 0);
        }
        float val[4];
#pragma unroll
        for (int r = 0; r < 4; ++r) {
          float vm = fmaxf(a0[r], a1[r]);
          float hp = fmaxf(vm, __shfl_xor(vm, 1));
          val[r] = fmaxf(hp + bias2[r], 0.f);
        }
        if ((col & 1) == 0) {
          int px = h * 8 + (col >> 1);
#pragma unroll
          for (int r = 0; r < 4; ++r)
            hcat[((size_t)g * 48 + lvl * 16 + q * 4 + r) * 256 + py * 16 + px] = f2bf(val[r]);
        }
      }
    }
  }
}

// ----------------------------- linear 0 via MFMA (unchanged) --------------------------------------------
__global__ __launch_bounds__(256) void lin0_kernel(
    const unsigned short* __restrict__ A, const unsigned short* __restrict__ WT,
    float* __restrict__ l0)
{
  __shared__ __align__(16) unsigned short sAb[64 * 72];
  __shared__ __align__(16) unsigned short sBb[64 * 72];
  const int rb = blockIdx.x * 64;
  const int cb = blockIdx.y * 64;
  const int k0 = blockIdx.z * 768;
  const int tid = threadIdx.x;
  const int lane = tid & 63, wave = tid >> 6;
  const int wm = wave >> 1, wn = wave & 1;
  const int c = lane & 15, kg = lane >> 4;
  const int srow = tid >> 2;
  const int skq  = (tid & 3) * 16;

  f32x4 acc[2][2];
#pragma unroll
  for (int i = 0; i < 2; ++i)
#pragma unroll
    for (int j = 0; j < 2; ++j) acc[i][j] = (f32x4){0.f, 0.f, 0.f, 0.f};

  for (int kt = 0; kt < 768; kt += 64) {
    {
      const unsigned short* src = A + (size_t)(rb + srow) * 12288 + k0 + kt + skq;
      s16x8 a0 = *reinterpret_cast<const s16x8*>(src);
      s16x8 a1 = *reinterpret_cast<const s16x8*>(src + 8);
      *reinterpret_cast<s16x8*>(sAb + srow * 72 + skq)     = a0;
      *reinterpret_cast<s16x8*>(sAb + srow * 72 + skq + 8) = a1;
    }
    {
      const unsigned short* src = WT + (size_t)(cb + srow) * 12288 + k0 + kt + skq;
      s16x8 w0 = *reinterpret_cast<const s16x8*>(src);
      s16x8 w1 = *reinterpret_cast<const s16x8*>(src + 8);
      *reinterpret_cast<s16x8*>(sBb + srow * 72 + skq)     = w0;
      *reinterpret_cast<s16x8*>(sBb + srow * 72 + skq + 8) = w1;
    }
    __syncthreads();

#pragma unroll
    for (int kb = 0; kb < 64; kb += 32) {
      s16x8 a0 = *reinterpret_cast<const s16x8*>(sAb + (wm * 32 +  0 + c) * 72 + kb + kg * 8);
      s16x8 a1 = *reinterpret_cast<const s16x8*>(sAb + (wm * 32 + 16 + c) * 72 + kb + kg * 8);
      s16x8 b0 = *reinterpret_cast<const s16x8*>(sBb + (wn * 32 +  0 + c) * 72 + kb + kg * 8);
      s16x8 b1 = *reinterpret_cast<const s16x8*>(sBb + (wn * 32 + 16 + c) * 72 + kb + kg * 8);
      acc[0][0] = __builtin_amdgcn_mfma_f32_16x16x32_bf16(a0, b0, acc[0][0], 0, 0, 0);
      acc[0][1] = __builtin_amdgcn_mfma_f32_16x16x32_bf16(a0, b1, acc[0][1], 0, 0, 0);
      acc[1][0] = __builtin_amdgcn_mfma_f32_16x16x32_bf16(a1, b0, acc[1][0], 0, 0, 0);
      acc[1][1] = __builtin_amdgcn_mfma_f32_16x16x32_bf16(a1, b1, acc[1][1], 0, 0, 0);
    }
    __syncthreads();
  }

#pragma unroll
  for (int i = 0; i < 2; ++i)
#pragma unroll
    for (int j = 0; j < 2; ++j)
#pragma unroll
      for (int r = 0; r < 4; ++r) {
        int row = rb + wm * 32 + i * 16 + kg * 4 + r;
        int col = cb + wn * 32 + j * 16 + c;
        atomicAdd(&l0[(size_t)row * 256 + col], acc[i][j][r]);
      }
}

// ----------------------------- head -----------------------------
__global__ __launch_bounds__(64) void head_kernel(
    const float* __restrict__ l0, const float* __restrict__ Wl1, const float* __restrict__ bl1,
    const float* __restrict__ Wsc, const float* __restrict__ bsc, float* __restrict__ out)
{
  __shared__ float sr[256];
  const int b = blockIdx.x, j = threadIdx.x;
  for (int k = j; k < 256; k += 64) sr[k] = fmaxf(l0[(size_t)b * 256 + k], 0.f);
  __syncthreads();
  float acc = bl1[j];
  for (int k = 0; k < 256; ++k) acc = fmaf(sr[k], Wl1[k * 64 + j], acc);
  float v = fmaxf(acc, 0.f) * Wsc[j];
#pragma unroll
  for (int off = 32; off > 0; off >>= 1) v += __shfl_down(v, off);
  if (j == 0) out[b] = 1.f / (1.f + expf(-(v + bsc[0])));
}

// ----------------------------- launch -----------------------------
extern "C" void kernel_launch(void* const* d_in, const int* in_sizes, int n_in,
                              void* d_out, int out_size, void* d_ws, size_t ws_size,
                              hipStream_t stream)
{
  (void)in_sizes; (void)n_in; (void)out_size; (void)ws_size;
  const float* x_q = (const float*)d_in[0];
  const float* x_c = (const float*)d_in[1];
  const int*   src_q = (const int*)d_in[2];
  const int*   dst_q = (const int*)d_in[3];
  const int*   src_c = (const int*)d_in[4];
  const int*   dst_c = (const int*)d_in[5];
  const float* Wg0 = (const float*)d_in[6];
  const float* bg0 = (const float*)d_in[7];
  const float* Wg1 = (const float*)d_in[8];
  const float* bg1 = (const float*)d_in[9];
  const float* Wg2 = (const float*)d_in[10];
  const float* bg2 = (const float*)d_in[11];
  const float* cw0 = (const float*)d_in[12];
  const float* cb0 = (const float*)d_in[13];
  const float* cw1 = (const float*)d_in[14];
  const float* cb1 = (const float*)d_in[15];
  const float* Wl0 = (const float*)d_in[16];
  const float* bl0 = (const float*)d_in[17];
  const float* Wl1 = (const float*)d_in[18];
  const float* bl1 = (const float*)d_in[19];
  const float* Wsc = (const float*)d_in[20];
  const float* bsc = (const float*)d_in[21];
  float* out = (float*)d_out;

  // workspace carve (float-granular; all u16 regions even-sized)
  float* ws = (float*)d_ws;
  unsigned short* qf0 = (unsigned short*)ws; ws += (size_t)NB * MM * 64 / 2;
  unsigned short* qf1 = (unsigned short*)ws; ws += (size_t)NB * MM * 32 / 2;
  unsigned short* qf2 = (unsigned short*)ws; ws += (size_t)NB * MM * 16 / 2;
  unsigned short* cf0 = (unsigned short*)ws; ws += (size_t)NB * MM * 64 / 2;
  unsigned short* cf1 = (unsigned short*)ws; ws += (size_t)NB * MM * 32 / 2;
  unsigned short* cf2 = (unsigned short*)ws; ws += (size_t)NB * MM * 16 / 2;
  unsigned short* hcat = (unsigned short*)ws; ws += (size_t)NB * 48 * 256 / 2;
  float* l0  = ws; ws += (size_t)NB * 256;
  unsigned short* packA  = (unsigned short*)ws; ws += 5376;   // 10752 bf16
  unsigned short* packW1 = (unsigned short*)ws; ws += 1536;   // 3072 bf16
  unsigned short* WgT    = (unsigned short*)ws; ws += 2304;   // 4608 bf16
  unsigned short* WT = (unsigned short*)ws; ws += (size_t)256 * 12288 / 2;

  prep_misc<<<584, 256, 0, stream>>>(cw1, cw0, bl0, Wg0, Wg1, Wg2, packA, packW1, WgT, l0);
  pack_wl0<<<dim3(192, 4), 256, 0, stream>>>(Wl0, WT);

  gcn_kernel<<<dim3(NB, 2), 256, 0, stream>>>(x_q, x_c, src_q, dst_q, src_c, dst_c,
      WgT, bg0, bg1, bg2, qf0, qf1, qf2, cf0, cf1, cf2);

  simconv_kernel<<<dim3(NB, 3), 256, 0, stream>>>(qf0, qf1, qf2, cf0, cf1, cf2,
      cb0, cb1, packA, packW1, hcat);

  lin0_kernel<<<dim3(8, 4, 16), 256, 0, stream>>>(hcat, WT, l0);
  head_kernel<<<NB, 64, 0, stream>>>(l0, Wl1, bl1, Wsc, bsc, out);
}

// Round 13
// 78.517 us; speedup vs baseline: 2.4580x; 1.1176x over previous
//
#include <hip/hip_runtime.h>
#include <math.h>

#define NB 512      // graph pairs
#define MM 64       // nodes per graph
#define EPGc 512    // edges per graph

typedef __attribute__((ext_vector_type(8))) short s16x8;
typedef __attribute__((ext_vector_type(4))) float f32x4;

__device__ __forceinline__ unsigned short f2bf(float f) {
  union { float f; unsigned int u; } c; c.f = f;
  unsigned int u = c.u;
  return (unsigned short)((u + 0x7FFFu + ((u >> 16) & 1u)) >> 16);   // RNE
}
__device__ __forceinline__ float bf2f(unsigned short h) {
  union { unsigned int u; float f; } c; c.u = ((unsigned int)h) << 16;
  return c.f;
}

// ----------------------------- GCN via MFMA (unchanged, verified R12) ----------------------------------
template<int Fin, int Fout, bool RELU>
__device__ __forceinline__ void gcn_layer_mfma(
    const unsigned short* __restrict__ WT, const float* __restrict__ bias,
    unsigned short* hbuf, unsigned short* stT, const unsigned short* Ab,
    unsigned short* __restrict__ outG, int g, int tid)
{
  const int lane = tid & 63, w = tid >> 6;
  const int c = lane & 15, q = lane >> 4;
  constexpr int NT = Fout / 16;
  constexpr int KS = Fin / 32;

  // GEMM1: st = h @ W -> stT[fout][node]
#pragma unroll
  for (int nt = 0; nt < NT; ++nt) {
    f32x4 acc = {0.f, 0.f, 0.f, 0.f};
#pragma unroll
    for (int ks = 0; ks < KS; ++ks) {
      s16x8 a = *reinterpret_cast<const s16x8*>(hbuf + (w * 16 + c) * 72 + ks * 32 + q * 8);
      s16x8 b = *reinterpret_cast<const s16x8*>(WT + (nt * 16 + c) * Fin + ks * 32 + q * 8);
      acc = __builtin_amdgcn_mfma_f32_16x16x32_bf16(a, b, acc, 0, 0, 0);
    }
    unsigned int w0 = (unsigned int)f2bf(acc[0]) | ((unsigned int)f2bf(acc[1]) << 16);
    unsigned int w1 = (unsigned int)f2bf(acc[2]) | ((unsigned int)f2bf(acc[3]) << 16);
    *reinterpret_cast<uint2*>(stT + (nt * 16 + c) * 72 + w * 16 + q * 4) = make_uint2(w0, w1);
  }
  __syncthreads();

  // GEMM2: out[f][dst] = sum_src st[src][f] * A[dst][src]
#pragma unroll
  for (int mt = 0; mt < NT; ++mt) {
    f32x4 acc = {0.f, 0.f, 0.f, 0.f};
#pragma unroll
    for (int ks = 0; ks < 2; ++ks) {
      s16x8 a = *reinterpret_cast<const s16x8*>(stT + (mt * 16 + c) * 72 + ks * 32 + q * 8);
      s16x8 b = *reinterpret_cast<const s16x8*>(Ab + (w * 16 + c) * 72 + ks * 32 + q * 8);
      acc = __builtin_amdgcn_mfma_f32_16x16x32_bf16(a, b, acc, 0, 0, 0);
    }
    const int node = w * 16 + c, f0 = mt * 16 + q * 4;
    unsigned short pk[4], pr[4];
#pragma unroll
    for (int r = 0; r < 4; ++r) {
      float v = acc[r] + bias[f0 + r];
      pk[r] = f2bf(v);
      pr[r] = f2bf(fmaxf(v, 0.f));
    }
    *reinterpret_cast<uint2*>(outG + (size_t)(g * MM + node) * Fout + f0) =
        make_uint2((unsigned int)pk[0] | ((unsigned int)pk[1] << 16),
                   (unsigned int)pk[2] | ((unsigned int)pk[3] << 16));
    if (RELU)
      *reinterpret_cast<uint2*>(hbuf + node * 72 + f0) =
          make_uint2((unsigned int)pr[0] | ((unsigned int)pr[1] << 16),
                     (unsigned int)pr[2] | ((unsigned int)pr[3] << 16));
  }
  __syncthreads();
}

__global__ __launch_bounds__(256) void gcn_kernel(
    const float* __restrict__ xq, const float* __restrict__ xc,
    const int* __restrict__ srcq, const int* __restrict__ dstq,
    const int* __restrict__ srcc, const int* __restrict__ dstc,
    const unsigned short* __restrict__ WgT,
    const float* __restrict__ bg0, const float* __restrict__ bg1, const float* __restrict__ bg2,
    unsigned short* __restrict__ qf0, unsigned short* __restrict__ qf1,
    unsigned short* __restrict__ qf2, unsigned short* __restrict__ cf0,
    unsigned short* __restrict__ cf1, unsigned short* __restrict__ cf2)
{
  __shared__ __align__(16) unsigned short smem[13824];  // hbuf|stT|Ab, each [64][72]
  __shared__ float sDinv[MM];
  __shared__ int sDeg[MM];
  unsigned short* hbuf = smem;
  unsigned short* stT  = smem + 4608;
  unsigned short* Ab   = smem + 9216;
  float* sAf = reinterpret_cast<float*>(smem);   // [64][68] fp32, aliases hbuf+stT (build phase only)

  const int g = blockIdx.x;
  const int which = blockIdx.y;
  const float* x = which ? xc : xq;
  const int* src = which ? srcc : srcq;
  const int* dst = which ? dstc : dstq;
  unsigned short* f0p = which ? cf0 : qf0;
  unsigned short* f1p = which ? cf1 : qf1;
  unsigned short* f2p = which ? cf2 : qf2;
  const int tid = threadIdx.x;

  for (int i = tid; i < 64 * 68; i += 256) sAf[i] = 0.f;
  if (tid < MM) sDeg[tid] = 1;
  __syncthreads();
  for (int e = tid; e < EPGc; e += 256)
    atomicAdd(&sDeg[dst[g * EPGc + e] - g * MM], 1);
  __syncthreads();
  if (tid < MM) sDinv[tid] = rsqrtf((float)sDeg[tid]);
  __syncthreads();
  for (int e = tid; e < EPGc; e += 256) {
    int s = src[g * EPGc + e] - g * MM;
    int d = dst[g * EPGc + e] - g * MM;
    atomicAdd(&sAf[d * 68 + s], sDinv[s] * sDinv[d]);
  }
  if (tid < MM) atomicAdd(&sAf[tid * 68 + tid], sDinv[tid] * sDinv[tid]);
  __syncthreads();
  for (int i = tid; i < 4096; i += 256) {
    int r = i >> 6, s = i & 63;
    Ab[r * 72 + s] = f2bf(sAf[r * 68 + s]);
  }
  __syncthreads();
  {
    const float* xs = x + (size_t)g * 2048 + tid * 8;
    float4 v0 = *reinterpret_cast<const float4*>(xs);
    float4 v1 = *reinterpret_cast<const float4*>(xs + 4);
    s16x8 p;
    p[0] = (short)f2bf(v0.x); p[1] = (short)f2bf(v0.y); p[2] = (short)f2bf(v0.z); p[3] = (short)f2bf(v0.w);
    p[4] = (short)f2bf(v1.x); p[5] = (short)f2bf(v1.y); p[6] = (short)f2bf(v1.z); p[7] = (short)f2bf(v1.w);
    int node = tid >> 2, k = (tid & 3) * 8;
    *reinterpret_cast<s16x8*>(hbuf + node * 72 + k) = p;
  }
  __syncthreads();

  gcn_layer_mfma<32, 64, true >(WgT,        bg0, hbuf, stT, Ab, f0p, g, tid);
  gcn_layer_mfma<64, 32, true >(WgT + 2048, bg1, hbuf, stT, Ab, f1p, g, tid);
  gcn_layer_mfma<32, 16, false>(WgT + 4096, bg2, hbuf, stT, Ab, f2p, g, tid);
}

// ----------------------------- merged prep: pack_w + pack_w1 + WgT + pack_wl0 --------------------------
// grid: [0,42) conv2 packA; [42,54) conv1 packW1; [54,72) WgT; [72,840) Wl0 transpose
__global__ __launch_bounds__(256) void prep_misc(
    const float* __restrict__ cw1, const float* __restrict__ cw0,
    const float* __restrict__ Wg0, const float* __restrict__ Wg1, const float* __restrict__ Wg2,
    const float* __restrict__ Wl0,
    unsigned short* __restrict__ packA, unsigned short* __restrict__ packW1,
    unsigned short* __restrict__ WgT, unsigned short* __restrict__ WT)
{
  __shared__ float tile[64][65];
  const int b = blockIdx.x, t = threadIdx.x;
  if (b < 42) {                        // pack_w: conv2 A-frag
    int i = b * 256 + t;
    if (i < 10752) {
      int j = i & 7, l = (i >> 3) & 63, g = (i >> 9) % 7, lvl = i / 3584;
      int oc = l & 15, sg = l >> 4;
      int s = g * 4 + sg;
      float v = 0.f;
      if (s < 25) v = cw1[((size_t)(lvl * 16 + oc) * 8 + j) * 25 + s];
      packA[i] = f2bf(v);
    }
    return;
  }
  if (b < 54) {                        // pack_w1: conv1 COL-SHIFT A-frag
    int i = (b - 42) * 256 + t;
    if (i < 3072) {
      int j = i & 7, lane = (i >> 3) & 63, gg = (i >> 9) & 1, lvl = i >> 10;
      int m = lane & 15, q = lane >> 4;
      int u = gg * 4 + q;
      int oc = m & 7;
      float v = 0.f;
      if (u < 5) {
        if (m < 8) { if (j < 5) v = cw0[((size_t)(lvl * 8 + oc)) * 25 + u * 5 + j]; }
        else       { if (j >= 1 && j <= 5) v = cw0[((size_t)(lvl * 8 + oc)) * 25 + u * 5 + (j - 1)]; }
      }
      packW1[i] = f2bf(v);
    }
    return;
  }
  if (b < 72) {                        // pack WgT: transposed bf16 GCN weights
    int i = (b - 54) * 256 + t;
    if (i < 2048) {
      int n = i >> 5, k = i & 31;
      WgT[i] = f2bf(Wg0[k * 64 + n]);
    } else if (i < 4096) {
      int j = i - 2048, n = j >> 6, k = j & 63;
      WgT[i] = f2bf(Wg1[k * 32 + n]);
    } else if (i < 4608) {
      int j = i - 4096, n = j >> 5, k = j & 31;
      WgT[i] = f2bf(Wg2[k * 16 + n]);
    }
    return;
  }
  {                                    // pack_wl0: Wl0 -> bf16 WT[n][k]
    int bb = b - 72;                   // 768 blocks: 192 kb x 4 nb
    const int kb = (bb % 192) * 64;
    const int nb = (bb / 192) * 64;
#pragma unroll
    for (int i = 0; i < 16; ++i) {
      int idx = i * 256 + t, kk = idx >> 6, nn = idx & 63;
      tile[kk][nn] = Wl0[(size_t)(kb + kk) * 256 + nb + nn];
    }
    __syncthreads();
#pragma unroll
    for (int i = 0; i < 16; ++i) {
      int idx = i * 256 + t, nn = idx >> 6, kk = idx & 63;
      WT[(size_t)(nb + nn) * 12288 + kb + kk] = f2bf(tile[kk][nn]);
    }
  }
}

// ----------------------------- fused sim + conv1 + conv2 (unchanged, verified R11/R12) ------------------
template<int F>
__device__ __forceinline__ void sim_mfma(const unsigned short* __restrict__ qf,
    const unsigned short* __restrict__ cf, unsigned short* qbf, unsigned short* cbf,
    unsigned short* cp, int g, int tid)
{
  constexpr int SQ = (F == 16) ? 40 : F + 8;
  {
    unsigned int* z = reinterpret_cast<unsigned int*>(cp);
    for (int i = tid; i < 2880; i += 256) z[i] = 0u;
  }
  for (int i = tid; i < 64 * F / 8; i += 256) {
    int row = (i * 8) / F, k = (i * 8) % F;
    s16x8 qv = *reinterpret_cast<const s16x8*>(qf + (size_t)g * 64 * F + i * 8);
    s16x8 cv = *reinterpret_cast<const s16x8*>(cf + (size_t)g * 64 * F + i * 8);
    *reinterpret_cast<s16x8*>(qbf + row * SQ + k) = qv;
    *reinterpret_cast<s16x8*>(cbf + row * SQ + k) = cv;
  }
  if (F == 16) {
    for (int i = tid; i < 128; i += 256) {
      int row = i >> 1, h = (i & 1) * 8;
      s16x8 zz = {0, 0, 0, 0, 0, 0, 0, 0};
      *reinterpret_cast<s16x8*>(qbf + row * SQ + 16 + h) = zz;
      *reinterpret_cast<s16x8*>(cbf + row * SQ + 16 + h) = zz;
    }
  }
  __syncthreads();

  const int lane = tid & 63, wave = tid >> 6;
  const int c = lane & 15, q = lane >> 4;
  constexpr int NK = (F == 64) ? 2 : 1;

  f32x4 acc[4];
#pragma unroll
  for (int nt = 0; nt < 4; ++nt) acc[nt] = (f32x4){0.f, 0.f, 0.f, 0.f};
#pragma unroll
  for (int ks = 0; ks < NK; ++ks) {
    s16x8 af = *reinterpret_cast<const s16x8*>(qbf + (wave * 16 + c) * SQ + ks * 32 + q * 8);
#pragma unroll
    for (int nt = 0; nt < 4; ++nt) {
      s16x8 bf = *reinterpret_cast<const s16x8*>(cbf + (nt * 16 + c) * SQ + ks * 32 + q * 8);
      acc[nt] = __builtin_amdgcn_mfma_f32_16x16x32_bf16(af, bf, acc[nt], 0, 0, 0);
    }
  }
#pragma unroll
  for (int nt = 0; nt < 4; ++nt)
#pragma unroll
    for (int r = 0; r < 4; ++r)
      cp[(wave * 16 + q * 4 + r + 2) * 80 + nt * 16 + c + 2] = f2bf(acc[nt][r]);
  __syncthreads();
}

__device__ __forceinline__ void conv1_mfma(const unsigned short* cp,
    unsigned short* p1u, const unsigned short* __restrict__ packW1,
    const float* __restrict__ cb0, int lvl, int tid)
{
  const int lane = tid & 63, wave = tid >> 6;
  const int c = lane & 15, q = lane >> 4;

  for (int h = tid; h < 272; h += 256) {
    int r, cc;
    if (h < 72)       { r = h / 36;             cc = h % 36; }
    else if (h < 144) { r = 34 + (h - 72) / 36; cc = (h - 72) % 36; }
    else { int z = h - 144; r = 2 + (z >> 2); int wq = z & 3; cc = (wq < 2) ? wq : 32 + wq; }
    s16x8 zz = {0, 0, 0, 0, 0, 0, 0, 0};
    *reinterpret_cast<s16x8*>(p1u + (r * 36 + cc) * 8) = zz;
  }

  s16x8 aw0 = *reinterpret_cast<const s16x8*>(packW1 + ((size_t)(lvl * 2 + 0) * 64 + lane) * 8);
  s16x8 aw1 = *reinterpret_cast<const s16x8*>(packW1 + ((size_t)(lvl * 2 + 1) * 64 + lane) * 8);
  float bias[4];
#pragma unroll
  for (int r = 0; r < 4; ++r) bias[r] = cb0[lvl * 8 + (q & 1) * 4 + r];

  const unsigned int* b32 = reinterpret_cast<const unsigned int*>(cp);

  for (int pp = 0; pp < 8; ++pp) {
    const int Y = wave * 8 + pp;
    const int y0 = 2 * Y;
#pragma unroll
    for (int Xi = 0; Xi < 2; ++Xi) {
      const int P = Xi * 16 + c;
      const int col = P;
      const int r00 = (y0 + q) * 40 + col;
      const int r01 = (y0 + 4 + q) * 40 + col;
      const int r10 = (y0 + 1 + q) * 40 + col;
      const int r11 = (y0 + 5 + q) * 40 + col;
      union { unsigned int w[4]; s16x8 v; } f00, f01, f10, f11;
#pragma unroll
      for (int k = 0; k < 4; ++k) {
        f00.w[k] = b32[r00 + k]; f01.w[k] = b32[r01 + k];
        f10.w[k] = b32[r10 + k]; f11.w[k] = b32[r11 + k];
      }
      f32x4 a0 = {0.f, 0.f, 0.f, 0.f}, a1 = {0.f, 0.f, 0.f, 0.f};
      a0 = __builtin_amdgcn_mfma_f32_16x16x32_bf16(aw0, f00.v, a0, 0, 0, 0);
      a0 = __builtin_amdgcn_mfma_f32_16x16x32_bf16(aw1, f01.v, a0, 0, 0, 0);
      a1 = __builtin_amdgcn_mfma_f32_16x16x32_bf16(aw0, f10.v, a1, 0, 0, 0);
      a1 = __builtin_amdgcn_mfma_f32_16x16x32_bf16(aw1, f11.v, a1, 0, 0, 0);
      float pv[4];
#pragma unroll
      for (int r = 0; r < 4; ++r) {
        float vm = fmaxf(a0[r], a1[r]);
        float hp = fmaxf(vm, __shfl_xor(vm, 32));
        pv[r] = fmaxf(hp + bias[r], 0.f);
      }
      if (q < 2) {
        unsigned short pk[4];
#pragma unroll
        for (int r = 0; r < 4; ++r) pk[r] = f2bf(pv[r]);
        unsigned int w0 = (unsigned int)pk[0] | ((unsigned int)pk[1] << 16);
        unsigned int w1 = (unsigned int)pk[2] | ((unsigned int)pk[3] << 16);
        *reinterpret_cast<uint2*>(p1u + (((Y + 2) * 36) + (P + 2)) * 8 + q * 4) =
            make_uint2(w0, w1);
      }
    }
  }
  __syncthreads();
}

__global__ __launch_bounds__(256) void simconv_kernel(
    const unsigned short* __restrict__ qf0, const unsigned short* __restrict__ qf1,
    const unsigned short* __restrict__ qf2, const unsigned short* __restrict__ cf0,
    const unsigned short* __restrict__ cf1, const unsigned short* __restrict__ cf2,
    const float* __restrict__ cb0, const float* __restrict__ cb1,
    const unsigned short* __restrict__ packA, const unsigned short* __restrict__ packW1,
    unsigned short* __restrict__ hcat)
{
  __shared__ __align__(16) unsigned short smem[16128];
  unsigned short* qbf = smem;
  unsigned short* cbf = smem + 4608;
  unsigned short* p1u = smem;
  unsigned short* cp  = smem + 10368;

  const int g = blockIdx.x, lvl = blockIdx.y, tid = threadIdx.x;

  if (lvl == 0)      sim_mfma<64>(qf0, cf0, qbf, cbf, cp, g, tid);
  else if (lvl == 1) sim_mfma<32>(qf1, cf1, qbf, cbf, cp, g, tid);
  else               sim_mfma<16>(qf2, cf2, qbf, cbf, cp, g, tid);

  conv1_mfma(cp, p1u, packW1, cb0, lvl, tid);

  {
    const int lane = tid & 63, wave = tid >> 6;
    const int col = lane & 15, q = lane >> 4;

    s16x8 afr[7];
#pragma unroll
    for (int gg = 0; gg < 7; ++gg)
      afr[gg] = *reinterpret_cast<const s16x8*>(packA + ((size_t)(lvl * 7 + gg) * 64 + lane) * 8);

    int off[7];
#pragma unroll
    for (int gg = 0; gg < 7; ++gg) {
      int s = gg * 4 + q; if (s > 24) s = 24;
      off[gg] = (s / 5) * 288 + (s % 5) * 8;
    }
    float bias2[4];
#pragma unroll
    for (int r = 0; r < 4; ++r) bias2[r] = cb1[lvl * 16 + q * 4 + r];

    for (int pq = 0; pq < 4; ++pq) {
      const int py = wave * 4 + pq;
#pragma unroll
      for (int h = 0; h < 2; ++h) {
        const int base0 = (2 * py) * 288 + h * 128 + col * 8;
        const int base1 = base0 + 288;
        f32x4 a0 = {0.f, 0.f, 0.f, 0.f}, a1 = {0.f, 0.f, 0.f, 0.f};
#pragma unroll
        for (int gg = 0; gg < 7; ++gg) {
          s16x8 b0 = *reinterpret_cast<const s16x8*>(p1u + base0 + off[gg]);
          a0 = __builtin_amdgcn_mfma_f32_16x16x32_bf16(afr[gg], b0, a0, 0, 0, 0);
          s16x8 b1 = *reinterpret_cast<const s16x8*>(p1u + base1 + off[gg]);
          a1 = __builtin_amdgcn_mfma_f32_16x16x32_bf16(afr[gg], b1, a1, 0, 0, 0);
        }
        float val[4];
#pragma unroll
        for (int r = 0; r < 4; ++r) {
          float vm = fmaxf(a0[r], a1[r]);
          float hp = fmaxf(vm, __shfl_xor(vm, 1));
          val[r] = fmaxf(hp + bias2[r], 0.f);
        }
        if ((col & 1) == 0) {
          int px = h * 8 + (col >> 1);
#pragma unroll
          for (int r = 0; r < 4; ++r)
            hcat[((size_t)g * 48 + lvl * 16 + q * 4 + r) * 256 + py * 16 + px] = f2bf(val[r]);
        }
      }
    }
  }
}

// ----------------------------- linear 0 via MFMA: non-atomic split-K partials ---------------------------
__global__ __launch_bounds__(256) void lin0_kernel(
    const unsigned short* __restrict__ A, const unsigned short* __restrict__ WT,
    float* __restrict__ part)
{
  __shared__ __align__(16) unsigned short sAb[64 * 72];
  __shared__ __align__(16) unsigned short sBb[64 * 72];
  const int rb = blockIdx.x * 64;
  const int cb = blockIdx.y * 64;
  const int k0 = blockIdx.z * 768;
  const int tid = threadIdx.x;
  const int lane = tid & 63, wave = tid >> 6;
  const int wm = wave >> 1, wn = wave & 1;
  const int c = lane & 15, kg = lane >> 4;
  const int srow = tid >> 2;
  const int skq  = (tid & 3) * 16;

  f32x4 acc[2][2];
#pragma unroll
  for (int i = 0; i < 2; ++i)
#pragma unroll
    for (int j = 0; j < 2; ++j) acc[i][j] = (f32x4){0.f, 0.f, 0.f, 0.f};

  for (int kt = 0; kt < 768; kt += 64) {
    {
      const unsigned short* src = A + (size_t)(rb + srow) * 12288 + k0 + kt + skq;
      s16x8 a0 = *reinterpret_cast<const s16x8*>(src);
      s16x8 a1 = *reinterpret_cast<const s16x8*>(src + 8);
      *reinterpret_cast<s16x8*>(sAb + srow * 72 + skq)     = a0;
      *reinterpret_cast<s16x8*>(sAb + srow * 72 + skq + 8) = a1;
    }
    {
      const unsigned short* src = WT + (size_t)(cb + srow) * 12288 + k0 + kt + skq;
      s16x8 w0 = *reinterpret_cast<const s16x8*>(src);
      s16x8 w1 = *reinterpret_cast<const s16x8*>(src + 8);
      *reinterpret_cast<s16x8*>(sBb + srow * 72 + skq)     = w0;
      *reinterpret_cast<s16x8*>(sBb + srow * 72 + skq + 8) = w1;
    }
    __syncthreads();

#pragma unroll
    for (int kb = 0; kb < 64; kb += 32) {
      s16x8 a0 = *reinterpret_cast<const s16x8*>(sAb + (wm * 32 +  0 + c) * 72 + kb + kg * 8);
      s16x8 a1 = *reinterpret_cast<const s16x8*>(sAb + (wm * 32 + 16 + c) * 72 + kb + kg * 8);
      s16x8 b0 = *reinterpret_cast<const s16x8*>(sBb + (wn * 32 +  0 + c) * 72 + kb + kg * 8);
      s16x8 b1 = *reinterpret_cast<const s16x8*>(sBb + (wn * 32 + 16 + c) * 72 + kb + kg * 8);
      acc[0][0] = __builtin_amdgcn_mfma_f32_16x16x32_bf16(a0, b0, acc[0][0], 0, 0, 0);
      acc[0][1] = __builtin_amdgcn_mfma_f32_16x16x32_bf16(a0, b1, acc[0][1], 0, 0, 0);
      acc[1][0] = __builtin_amdgcn_mfma_f32_16x16x32_bf16(a1, b0, acc[1][0], 0, 0, 0);
      acc[1][1] = __builtin_amdgcn_mfma_f32_16x16x32_bf16(a1, b1, acc[1][1], 0, 0, 0);
    }
    __syncthreads();
  }

  // non-atomic: each K-split writes its own partial slice
  float* dstp = part + (size_t)blockIdx.z * 512 * 256;
#pragma unroll
  for (int i = 0; i < 2; ++i)
#pragma unroll
    for (int j = 0; j < 2; ++j)
#pragma unroll
      for (int r = 0; r < 4; ++r) {
        int row = rb + wm * 32 + i * 16 + kg * 4 + r;
        int col = cb + wn * 32 + j * 16 + c;
        dstp[(size_t)row * 256 + col] = acc[i][j][r];
      }
}

// ----------------------------- head: 16-way partial reduce + bias + relu -> lin1 -> score ---------------
__global__ __launch_bounds__(64) void head_kernel(
    const float* __restrict__ part, const float* __restrict__ bl0,
    const float* __restrict__ Wl1, const float* __restrict__ bl1,
    const float* __restrict__ Wsc, const float* __restrict__ bsc, float* __restrict__ out)
{
  __shared__ float sr[256];
  const int b = blockIdx.x, j = threadIdx.x;
  {
    float4 s = *reinterpret_cast<const float4*>(bl0 + j * 4);
#pragma unroll
    for (int z = 0; z < 16; ++z) {
      float4 p = *reinterpret_cast<const float4*>(part + ((size_t)z * 512 + b) * 256 + j * 4);
      s.x += p.x; s.y += p.y; s.z += p.z; s.w += p.w;
    }
    sr[j * 4 + 0] = fmaxf(s.x, 0.f);
    sr[j * 4 + 1] = fmaxf(s.y, 0.f);
    sr[j * 4 + 2] = fmaxf(s.z, 0.f);
    sr[j * 4 + 3] = fmaxf(s.w, 0.f);
  }
  __syncthreads();
  float acc = bl1[j];
  for (int k = 0; k < 256; ++k) acc = fmaf(sr[k], Wl1[k * 64 + j], acc);
  float v = fmaxf(acc, 0.f) * Wsc[j];
#pragma unroll
  for (int off = 32; off > 0; off >>= 1) v += __shfl_down(v, off);
  if (j == 0) out[b] = 1.f / (1.f + expf(-(v + bsc[0])));
}

// ----------------------------- launch -----------------------------
extern "C" void kernel_launch(void* const* d_in, const int* in_sizes, int n_in,
                              void* d_out, int out_size, void* d_ws, size_t ws_size,
                              hipStream_t stream)
{
  (void)in_sizes; (void)n_in; (void)out_size; (void)ws_size;
  const float* x_q = (const float*)d_in[0];
  const float* x_c = (const float*)d_in[1];
  const int*   src_q = (const int*)d_in[2];
  const int*   dst_q = (const int*)d_in[3];
  const int*   src_c = (const int*)d_in[4];
  const int*   dst_c = (const int*)d_in[5];
  const float* Wg0 = (const float*)d_in[6];
  const float* bg0 = (const float*)d_in[7];
  const float* Wg1 = (const float*)d_in[8];
  const float* bg1 = (const float*)d_in[9];
  const float* Wg2 = (const float*)d_in[10];
  const float* bg2 = (const float*)d_in[11];
  const float* cw0 = (const float*)d_in[12];
  const float* cb0 = (const float*)d_in[13];
  const float* cw1 = (const float*)d_in[14];
  const float* cb1 = (const float*)d_in[15];
  const float* Wl0 = (const float*)d_in[16];
  const float* bl0 = (const float*)d_in[17];
  const float* Wl1 = (const float*)d_in[18];
  const float* bl1 = (const float*)d_in[19];
  const float* Wsc = (const float*)d_in[20];
  const float* bsc = (const float*)d_in[21];
  float* out = (float*)d_out;

  // workspace carve (float-granular; all u16 regions even-sized)
  float* ws = (float*)d_ws;
  unsigned short* qf0 = (unsigned short*)ws; ws += (size_t)NB * MM * 64 / 2;
  unsigned short* qf1 = (unsigned short*)ws; ws += (size_t)NB * MM * 32 / 2;
  unsigned short* qf2 = (unsigned short*)ws; ws += (size_t)NB * MM * 16 / 2;
  unsigned short* cf0 = (unsigned short*)ws; ws += (size_t)NB * MM * 64 / 2;
  unsigned short* cf1 = (unsigned short*)ws; ws += (size_t)NB * MM * 32 / 2;
  unsigned short* cf2 = (unsigned short*)ws; ws += (size_t)NB * MM * 16 / 2;
  unsigned short* hcat = (unsigned short*)ws; ws += (size_t)NB * 48 * 256 / 2;
  float* part = ws; ws += (size_t)16 * 512 * 256;              // 8.4 MB split-K partials
  unsigned short* packA  = (unsigned short*)ws; ws += 5376;    // 10752 bf16
  unsigned short* packW1 = (unsigned short*)ws; ws += 1536;    // 3072 bf16
  unsigned short* WgT    = (unsigned short*)ws; ws += 2304;    // 4608 bf16
  unsigned short* WT = (unsigned short*)ws; ws += (size_t)256 * 12288 / 2;

  prep_misc<<<840, 256, 0, stream>>>(cw1, cw0, Wg0, Wg1, Wg2, Wl0,
                                     packA, packW1, WgT, WT);

  gcn_kernel<<<dim3(NB, 2), 256, 0, stream>>>(x_q, x_c, src_q, dst_q, src_c, dst_c,
      WgT, bg0, bg1, bg2, qf0, qf1, qf2, cf0, cf1, cf2);

  simconv_kernel<<<dim3(NB, 3), 256, 0, stream>>>(qf0, qf1, qf2, cf0, cf1, cf2,
      cb0, cb1, packA, packW1, hcat);

  lin0_kernel<<<dim3(8, 4, 16), 256, 0, stream>>>(hcat, WT, part);
  head_kernel<<<NB, 64, 0, stream>>>(part, bl0, Wl1, bl1, Wsc, bsc, out);
}